// Round 2
// baseline (3910.826 us; speedup 1.0000x reference)
//
#include <hip/hip_runtime.h>

// GConvGRU (ChebConv K=3, GRU with H=0) on MI355X.
// H=0 => all Wh* convs reduce to their biases, R is dead, and
// out = (1 - sigmoid(Cz + bhz)) * tanh(Ch + bhh), where Cz/Ch are
// ChebConvs of x with Wxz/Wxh sharing the basis Tx0=x, Tx1=P x,
// Tx2=2 P Tx1 - x, with P = -D^{-1/2} A D^{-1/2} (self-loops zeroed).
//
// NOTE: harness passes integer inputs as int32 (edge_index is const int*).

static constexpr int BLK = 256;

__device__ __forceinline__ void atomAddF(float* p, float v) {
    unsafeAtomicAdd(p, v);  // hw global_atomic_add_f32 on gfx950
}

// Zero a float4-aligned region (replaces hipMemsetAsync for capture safety).
__global__ void k_zero(float4* __restrict__ p, long long n4)
{
    long long i = (long long)blockIdx.x * blockDim.x + threadIdx.x;
    long long stride = (long long)gridDim.x * blockDim.x;
    for (; i < n4; i += stride)
        p[i] = make_float4(0.f, 0.f, 0.f, 0.f);
}

// Pass 1: degree accumulation: deg[src] += w (self-loops excluded).
__global__ void k_deg(const int* __restrict__ srcp, const int* __restrict__ dstp,
                      const float* __restrict__ w, float* __restrict__ deg,
                      long long ne)
{
    const long long ng = (ne + 3) >> 2;
    const long long stride = (long long)gridDim.x * blockDim.x;
    for (long long g = (long long)blockIdx.x * blockDim.x + threadIdx.x; g < ng; g += stride) {
        const long long e = g << 2;
        if (e + 3 < ne) {
            int4 s4 = *(const int4*)(srcp + e);
            int4 d4 = *(const int4*)(dstp + e);
            float4 w4 = *(const float4*)(w + e);
            if (s4.x != d4.x) atomAddF(&deg[s4.x], w4.x);
            if (s4.y != d4.y) atomAddF(&deg[s4.y], w4.y);
            if (s4.z != d4.z) atomAddF(&deg[s4.z], w4.z);
            if (s4.w != d4.w) atomAddF(&deg[s4.w], w4.w);
        } else {
            for (long long q = e; q < ne; ++q) {
                int s = srcp[q], d = dstp[q];
                if (s != d) atomAddF(&deg[s], w[q]);
            }
        }
    }
}

// Pass 2: deg -> dinv in place.
__global__ void k_dinv(float* __restrict__ deg, int n)
{
    int i = blockIdx.x * blockDim.x + threadIdx.x;
    if (i < n) {
        float d = deg[i];
        deg[i] = (d > 0.0f) ? rsqrtf(d) : 0.0f;
    }
}

// Passes 3&4: acc[dst] += w_norm[e] * in[src], w_norm = -(dinv[s]*w*dinv[d]),
// self-loops zeroed.
__global__ void k_prop(const int* __restrict__ srcp, const int* __restrict__ dstp,
                       const float* __restrict__ w, const float* __restrict__ dinv,
                       const float2* __restrict__ xin, float* __restrict__ acc,
                       long long ne)
{
    const long long ng = (ne + 3) >> 2;
    const long long stride = (long long)gridDim.x * blockDim.x;
    for (long long g = (long long)blockIdx.x * blockDim.x + threadIdx.x; g < ng; g += stride) {
        const long long e = g << 2;
        if (e + 3 < ne) {
            int4 s4 = *(const int4*)(srcp + e);
            int4 d4 = *(const int4*)(dstp + e);
            float4 w4 = *(const float4*)(w + e);
            int s[4] = {s4.x, s4.y, s4.z, s4.w};
            int d[4] = {d4.x, d4.y, d4.z, d4.w};
            float wv[4] = {w4.x, w4.y, w4.z, w4.w};
#pragma unroll
            for (int j = 0; j < 4; ++j) {
                float wn = (s[j] != d[j]) ? -(dinv[s[j]] * wv[j] * dinv[d[j]]) : 0.0f;
                float2 xv = xin[s[j]];
                atomAddF(&acc[2 * d[j] + 0], wn * xv.x);
                atomAddF(&acc[2 * d[j] + 1], wn * xv.y);
            }
        } else {
            for (long long q = e; q < ne; ++q) {
                int ss = srcp[q], dd = dstp[q];
                float wn = (ss != dd) ? -(dinv[ss] * w[q] * dinv[dd]) : 0.0f;
                float2 xv = xin[ss];
                atomAddF(&acc[2 * dd + 0], wn * xv.x);
                atomAddF(&acc[2 * dd + 1], wn * xv.y);
            }
        }
    }
}

// Pass 5: Tx2 = 2*tx2acc - x; gates; out = (1 - sigmoid(z)) * tanh(h).
__global__ void k_final(const float2* __restrict__ x, const float2* __restrict__ tx1,
                        const float2* __restrict__ tx2a,
                        const float* __restrict__ Wxz, const float* __restrict__ Wxh,
                        const float* __restrict__ bxz, const float* __restrict__ bhz,
                        const float* __restrict__ bxh, const float* __restrict__ bhh,
                        float* __restrict__ out, int n)
{
    int i = blockIdx.x * blockDim.x + threadIdx.x;
    if (i >= n) return;
    float2 t0 = x[i];
    float2 t1 = tx1[i];
    float2 ta = tx2a[i];
    float t2x = 2.0f * ta.x - t0.x;
    float t2y = 2.0f * ta.y - t0.y;
    // W layout [3][2][1] -> idx k*2+c
    float z = t0.x * Wxz[0] + t0.y * Wxz[1]
            + t1.x * Wxz[2] + t1.y * Wxz[3]
            + t2x  * Wxz[4] + t2y  * Wxz[5] + bxz[0] + bhz[0];
    float h = t0.x * Wxh[0] + t0.y * Wxh[1]
            + t1.x * Wxh[2] + t1.y * Wxh[3]
            + t2x  * Wxh[4] + t2y  * Wxh[5] + bxh[0] + bhh[0];
    float zs = 1.0f / (1.0f + expf(-z));
    float ht = tanhf(h);
    out[i] = (1.0f - zs) * ht;
}

extern "C" void kernel_launch(void* const* d_in, const int* in_sizes, int n_in,
                              void* d_out, int out_size, void* d_ws, size_t ws_size,
                              hipStream_t stream)
{
    // setup_inputs() dict order:
    // 0 x, 1 edge_index, 2 edge_weights, 3 Wxz, 4 Wxr, 5 Wxh,
    // 6 Whz, 7 Whr, 8 Whh, 9 bxz, 10 bhz, 11 bxr, 12 bhr, 13 bxh, 14 bhh
    const float* x   = (const float*)d_in[0];
    const int*   ei  = (const int*)d_in[1];    // int32 on device
    const float* w   = (const float*)d_in[2];
    const float* Wxz = (const float*)d_in[3];
    const float* Wxh = (const float*)d_in[5];
    const float* bxz = (const float*)d_in[9];
    const float* bhz = (const float*)d_in[10];
    const float* bxh = (const float*)d_in[13];
    const float* bhh = (const float*)d_in[14];

    const int n = in_sizes[0] / 2;
    const long long ne = in_sizes[2];

    char* ws = (char*)d_ws;
    size_t off = 0;
    auto alloc = [&](size_t bytes) -> char* {
        char* p = ws + off;
        off = (off + bytes + 255) & ~(size_t)255;
        return p;
    };
    float* deg  = (float*)alloc((size_t)n * sizeof(float));      // becomes dinv
    float* tx1  = (float*)alloc((size_t)n * 2 * sizeof(float));
    float* tx2a = (float*)alloc((size_t)n * 2 * sizeof(float));
    const size_t zero_bytes = off;  // contiguous region to zero (256B multiple)

    const int* srcp = ei;
    const int* dstp = ei + ne;

    const int eblocks = 4096;
    const int nblocks = (n + BLK - 1) / BLK;
    const long long n4 = (long long)(zero_bytes / 16);

    k_zero<<<1024, BLK, 0, stream>>>((float4*)ws, n4);
    k_deg<<<eblocks, BLK, 0, stream>>>(srcp, dstp, w, deg, ne);
    k_dinv<<<nblocks, BLK, 0, stream>>>(deg, n);
    k_prop<<<eblocks, BLK, 0, stream>>>(srcp, dstp, w, deg,
                                        (const float2*)x, tx1, ne);
    k_prop<<<eblocks, BLK, 0, stream>>>(srcp, dstp, w, deg,
                                        (const float2*)tx1, tx2a, ne);
    k_final<<<nblocks, BLK, 0, stream>>>((const float2*)x, (const float2*)tx1,
                                         (const float2*)tx2a,
                                         Wxz, Wxh, bxz, bhz, bxh, bhh,
                                         (float*)d_out, n);
}

// Round 3
// 1416.894 us; speedup vs baseline: 2.7601x; 2.7601x over previous
//
#include <hip/hip_runtime.h>

// GConvGRU (ChebConv K=3, GRU with H=0) on MI355X.
// H=0 => out = (1 - sigmoid(Cz + bhz)) * tanh(Ch + bhh); Cz/Ch share the
// Chebyshev basis Tx0=x, Tx1=P x, Tx2=2 P Tx1 - x, P = -D^{-1/2} A D^{-1/2}.
//
// Round-2 counters: scattered global f32 atomics dominate (32M atomics ->
// 1.0 GB coherent write traffic per prop, 20 G atomics/s). This version
// removes ALL global float atomics via a bucket partition (counting sort by
// node>>8), then accumulates in LDS per 256-node bucket.

static constexpr int BLK = 256;
static constexpr int NBMAX = 2048;          // max buckets (n <= 2^19)
static constexpr long long CHUNK = 16384;   // edges per scatter block

__device__ __forceinline__ void atomAddF(float* p, float v) {
    unsafeAtomicAdd(p, v);
}

// ---------------- small utility kernels ----------------

__global__ void k_zero_ints(int* __restrict__ p, int n)
{
    int i = blockIdx.x * blockDim.x + threadIdx.x;
    int stride = gridDim.x * blockDim.x;
    for (; i < n; i += stride) p[i] = 0;
}

__global__ void k_zero_f4(float4* __restrict__ p, long long n4)
{
    long long i = (long long)blockIdx.x * blockDim.x + threadIdx.x;
    long long stride = (long long)gridDim.x * blockDim.x;
    for (; i < n4; i += stride) p[i] = make_float4(0.f, 0.f, 0.f, 0.f);
}

// ---------------- partition path ----------------

// Global bucket histograms for src and dst in one pass.
__global__ void k_hist(const int* __restrict__ srcp, const int* __restrict__ dstp,
                       int* __restrict__ histS, int* __restrict__ histD,
                       long long ne, int NB)
{
    __shared__ int lS[NBMAX];
    __shared__ int lD[NBMAX];
    for (int b = threadIdx.x; b < NB; b += blockDim.x) { lS[b] = 0; lD[b] = 0; }
    __syncthreads();

    const long long ng = (ne + 3) >> 2;
    const long long stride = (long long)gridDim.x * blockDim.x;
    for (long long g = (long long)blockIdx.x * blockDim.x + threadIdx.x; g < ng; g += stride) {
        const long long e = g << 2;
        if (e + 3 < ne) {
            int4 s4 = *(const int4*)(srcp + e);
            int4 d4 = *(const int4*)(dstp + e);
            atomicAdd(&lS[s4.x >> 8], 1); atomicAdd(&lS[s4.y >> 8], 1);
            atomicAdd(&lS[s4.z >> 8], 1); atomicAdd(&lS[s4.w >> 8], 1);
            atomicAdd(&lD[d4.x >> 8], 1); atomicAdd(&lD[d4.y >> 8], 1);
            atomicAdd(&lD[d4.z >> 8], 1); atomicAdd(&lD[d4.w >> 8], 1);
        } else {
            for (long long q = e; q < ne; ++q) {
                atomicAdd(&lS[srcp[q] >> 8], 1);
                atomicAdd(&lD[dstp[q] >> 8], 1);
            }
        }
    }
    __syncthreads();
    for (int b = threadIdx.x; b < NB; b += blockDim.x) {
        if (lS[b]) atomicAdd(&histS[b], lS[b]);
        if (lD[b]) atomicAdd(&histD[b], lD[b]);
    }
}

// Exclusive scan of hist -> base, and cursor = base. block 0: S, block 1: D.
__global__ void k_scan(const int* __restrict__ histS, int* __restrict__ baseS, int* __restrict__ curS,
                       const int* __restrict__ histD, int* __restrict__ baseD, int* __restrict__ curD,
                       int NB)
{
    const int* hist = (blockIdx.x == 0) ? histS : histD;
    int* base = (blockIdx.x == 0) ? baseS : baseD;
    int* cur  = (blockIdx.x == 0) ? curS  : curD;

    __shared__ int part[BLK];
    int t = threadIdx.x;
    int v[8];
    int s = 0;
#pragma unroll
    for (int j = 0; j < 8; ++j) {
        int idx = t * 8 + j;
        v[j] = (idx < NB) ? hist[idx] : 0;
        s += v[j];
    }
    part[t] = s;
    __syncthreads();
    // Hillis-Steele inclusive scan
    for (int off = 1; off < BLK; off <<= 1) {
        int val = (t >= off) ? part[t - off] : 0;
        __syncthreads();
        part[t] += val;
        __syncthreads();
    }
    int run = (t == 0) ? 0 : part[t - 1];
#pragma unroll
    for (int j = 0; j < 8; ++j) {
        int idx = t * 8 + j;
        if (idx < NB) { base[idx] = run; cur[idx] = run; run += v[j]; }
    }
}

// Scatter edges into per-bucket record arrays.
// MODE 0 (by src): rec = { srcLocal, w_eff }  (w_eff=0 for self-loops)
// MODE 1 (by dst): rec = { src | dstLocal<<19, wn }  wn = -(dinv[s]*w*dinv[d])
template <int MODE>
__global__ void k_scatter(const int* __restrict__ srcp, const int* __restrict__ dstp,
                          const float* __restrict__ w, const float* __restrict__ dinv,
                          int* __restrict__ cursor, uint2* __restrict__ recs,
                          long long ne, int NB)
{
    __shared__ int lbase[NBMAX];
    __shared__ int lrank[NBMAX];
    const long long cs = (long long)blockIdx.x * CHUNK;
    const long long ce = (cs + CHUNK < ne) ? cs + CHUNK : ne;
    if (cs >= ne) return;

    for (int b = threadIdx.x; b < NB; b += blockDim.x) { lbase[b] = 0; lrank[b] = 0; }
    __syncthreads();

    const int* keys = (MODE == 0) ? srcp : dstp;

    // pass 1: local histogram (reuse lbase as counter)
    for (long long i = cs + (long long)threadIdx.x * 4; i < ce; i += (long long)blockDim.x * 4) {
        if (i + 3 < ce) {
            int4 k4 = *(const int4*)(keys + i);
            atomicAdd(&lbase[k4.x >> 8], 1); atomicAdd(&lbase[k4.y >> 8], 1);
            atomicAdd(&lbase[k4.z >> 8], 1); atomicAdd(&lbase[k4.w >> 8], 1);
        } else {
            for (long long q = i; q < ce; ++q) atomicAdd(&lbase[keys[q] >> 8], 1);
        }
    }
    __syncthreads();
    // reserve per-bucket chunks
    for (int b = threadIdx.x; b < NB; b += blockDim.x) {
        int c = lbase[b];
        lbase[b] = (c > 0) ? atomicAdd(&cursor[b], c) : 0;
    }
    __syncthreads();
    // pass 2: rank + write records
    for (long long i = cs + (long long)threadIdx.x * 4; i < ce; i += (long long)blockDim.x * 4) {
        if (i + 3 < ce) {
            int4 s4 = *(const int4*)(srcp + i);
            int4 d4 = *(const int4*)(dstp + i);
            float4 w4 = *(const float4*)(w + i);
            int ss[4] = {s4.x, s4.y, s4.z, s4.w};
            int dd[4] = {d4.x, d4.y, d4.z, d4.w};
            float wv[4] = {w4.x, w4.y, w4.z, w4.w};
#pragma unroll
            for (int j = 0; j < 4; ++j) {
                int key = (MODE == 0) ? ss[j] : dd[j];
                int b = key >> 8;
                int r = atomicAdd(&lrank[b], 1);
                long long pos = (long long)lbase[b] + r;
                if (MODE == 0) {
                    float we = (ss[j] == dd[j]) ? 0.0f : wv[j];
                    recs[pos] = make_uint2((unsigned)(ss[j] & 255), __float_as_uint(we));
                } else {
                    float wn = (ss[j] == dd[j]) ? 0.0f
                             : -(dinv[ss[j]] * wv[j] * dinv[dd[j]]);
                    unsigned meta = (unsigned)ss[j] | ((unsigned)(dd[j] & 255) << 19);
                    recs[pos] = make_uint2(meta, __float_as_uint(wn));
                }
            }
        } else {
            for (long long q = i; q < ce; ++q) {
                int s = srcp[q], d = dstp[q];
                float wv = w[q];
                int key = (MODE == 0) ? s : d;
                int b = key >> 8;
                int r = atomicAdd(&lrank[b], 1);
                long long pos = (long long)lbase[b] + r;
                if (MODE == 0) {
                    float we = (s == d) ? 0.0f : wv;
                    recs[pos] = make_uint2((unsigned)(s & 255), __float_as_uint(we));
                } else {
                    float wn = (s == d) ? 0.0f : -(dinv[s] * wv * dinv[d]);
                    unsigned meta = (unsigned)s | ((unsigned)(d & 255) << 19);
                    recs[pos] = make_uint2(meta, __float_as_uint(wn));
                }
            }
        }
    }
}

// Per-bucket deg accumulation + dinv.
__global__ void k_degdinv(const uint2* __restrict__ recs, const int* __restrict__ base,
                          const int* __restrict__ hist, float* __restrict__ dinv, int n)
{
    __shared__ float lacc[256];
    const int b = blockIdx.x;
    lacc[threadIdx.x] = 0.0f;
    __syncthreads();
    const int st = base[b], cnt = hist[b];
    for (int r = threadIdx.x; r < cnt; r += blockDim.x) {
        uint2 rec = recs[(long long)st + r];
        atomicAdd(&lacc[rec.x & 255u], __uint_as_float(rec.y));
    }
    __syncthreads();
    int node = (b << 8) + threadIdx.x;
    if (node < n) {
        float dg = lacc[threadIdx.x];
        dinv[node] = (dg > 0.0f) ? rsqrtf(dg) : 0.0f;
    }
}

// Per-bucket propagation: out[dst] = sum wn * xin[src], LDS-accumulated.
__global__ void k_propb(const uint2* __restrict__ recs, const int* __restrict__ base,
                        const int* __restrict__ hist, const float2* __restrict__ xin,
                        float2* __restrict__ out, int n)
{
    __shared__ float laccx[256];
    __shared__ float laccy[256];
    const int b = blockIdx.x;
    laccx[threadIdx.x] = 0.0f;
    laccy[threadIdx.x] = 0.0f;
    __syncthreads();
    const int st = base[b], cnt = hist[b];
    for (int r = threadIdx.x; r < cnt; r += blockDim.x) {
        uint2 rec = recs[(long long)st + r];
        int src = (int)(rec.x & 0x7FFFFu);
        int dl  = (int)(rec.x >> 19);
        float wn = __uint_as_float(rec.y);
        float2 xv = xin[src];
        atomicAdd(&laccx[dl], wn * xv.x);
        atomicAdd(&laccy[dl], wn * xv.y);
    }
    __syncthreads();
    int node = (b << 8) + threadIdx.x;
    if (node < n) out[node] = make_float2(laccx[threadIdx.x], laccy[threadIdx.x]);
}

// ---------------- fallback path (global atomics) ----------------

__global__ void k_deg_atomic(const int* __restrict__ srcp, const int* __restrict__ dstp,
                             const float* __restrict__ w, float* __restrict__ deg,
                             long long ne)
{
    const long long ng = (ne + 3) >> 2;
    const long long stride = (long long)gridDim.x * blockDim.x;
    for (long long g = (long long)blockIdx.x * blockDim.x + threadIdx.x; g < ng; g += stride) {
        const long long e = g << 2;
        if (e + 3 < ne) {
            int4 s4 = *(const int4*)(srcp + e);
            int4 d4 = *(const int4*)(dstp + e);
            float4 w4 = *(const float4*)(w + e);
            if (s4.x != d4.x) atomAddF(&deg[s4.x], w4.x);
            if (s4.y != d4.y) atomAddF(&deg[s4.y], w4.y);
            if (s4.z != d4.z) atomAddF(&deg[s4.z], w4.z);
            if (s4.w != d4.w) atomAddF(&deg[s4.w], w4.w);
        } else {
            for (long long q = e; q < ne; ++q) {
                int s = srcp[q], d = dstp[q];
                if (s != d) atomAddF(&deg[s], w[q]);
            }
        }
    }
}

__global__ void k_dinv_inplace(float* __restrict__ deg, int n)
{
    int i = blockIdx.x * blockDim.x + threadIdx.x;
    if (i < n) {
        float d = deg[i];
        deg[i] = (d > 0.0f) ? rsqrtf(d) : 0.0f;
    }
}

__global__ void k_prop_atomic(const int* __restrict__ srcp, const int* __restrict__ dstp,
                              const float* __restrict__ w, const float* __restrict__ dinv,
                              const float2* __restrict__ xin, float* __restrict__ acc,
                              long long ne)
{
    const long long ng = (ne + 3) >> 2;
    const long long stride = (long long)gridDim.x * blockDim.x;
    for (long long g = (long long)blockIdx.x * blockDim.x + threadIdx.x; g < ng; g += stride) {
        const long long e = g << 2;
        if (e + 3 < ne) {
            int4 s4 = *(const int4*)(srcp + e);
            int4 d4 = *(const int4*)(dstp + e);
            float4 w4 = *(const float4*)(w + e);
            int s[4] = {s4.x, s4.y, s4.z, s4.w};
            int d[4] = {d4.x, d4.y, d4.z, d4.w};
            float wv[4] = {w4.x, w4.y, w4.z, w4.w};
#pragma unroll
            for (int j = 0; j < 4; ++j) {
                float wn = (s[j] != d[j]) ? -(dinv[s[j]] * wv[j] * dinv[d[j]]) : 0.0f;
                float2 xv = xin[s[j]];
                atomAddF(&acc[2 * d[j] + 0], wn * xv.x);
                atomAddF(&acc[2 * d[j] + 1], wn * xv.y);
            }
        } else {
            for (long long q = e; q < ne; ++q) {
                int ss = srcp[q], dd = dstp[q];
                float wn = (ss != dd) ? -(dinv[ss] * w[q] * dinv[dd]) : 0.0f;
                float2 xv = xin[ss];
                atomAddF(&acc[2 * dd + 0], wn * xv.x);
                atomAddF(&acc[2 * dd + 1], wn * xv.y);
            }
        }
    }
}

// ---------------- gate epilogue ----------------

__global__ void k_final(const float2* __restrict__ x, const float2* __restrict__ tx1,
                        const float2* __restrict__ tx2a,
                        const float* __restrict__ Wxz, const float* __restrict__ Wxh,
                        const float* __restrict__ bxz, const float* __restrict__ bhz,
                        const float* __restrict__ bxh, const float* __restrict__ bhh,
                        float* __restrict__ out, int n)
{
    int i = blockIdx.x * blockDim.x + threadIdx.x;
    if (i >= n) return;
    float2 t0 = x[i];
    float2 t1 = tx1[i];
    float2 ta = tx2a[i];
    float t2x = 2.0f * ta.x - t0.x;
    float t2y = 2.0f * ta.y - t0.y;
    float z = t0.x * Wxz[0] + t0.y * Wxz[1]
            + t1.x * Wxz[2] + t1.y * Wxz[3]
            + t2x  * Wxz[4] + t2y  * Wxz[5] + bxz[0] + bhz[0];
    float h = t0.x * Wxh[0] + t0.y * Wxh[1]
            + t1.x * Wxh[2] + t1.y * Wxh[3]
            + t2x  * Wxh[4] + t2y  * Wxh[5] + bxh[0] + bhh[0];
    float zs = 1.0f / (1.0f + expf(-z));
    float ht = tanhf(h);
    out[i] = (1.0f - zs) * ht;
}

// ---------------- launch ----------------

extern "C" void kernel_launch(void* const* d_in, const int* in_sizes, int n_in,
                              void* d_out, int out_size, void* d_ws, size_t ws_size,
                              hipStream_t stream)
{
    const float* x   = (const float*)d_in[0];
    const int*   ei  = (const int*)d_in[1];
    const float* w   = (const float*)d_in[2];
    const float* Wxz = (const float*)d_in[3];
    const float* Wxh = (const float*)d_in[5];
    const float* bxz = (const float*)d_in[9];
    const float* bhz = (const float*)d_in[10];
    const float* bxh = (const float*)d_in[13];
    const float* bhh = (const float*)d_in[14];

    const int n = in_sizes[0] / 2;
    const long long ne = in_sizes[2];
    const int* srcp = ei;
    const int* dstp = ei + ne;
    const int nblocks = (n + BLK - 1) / BLK;

    char* ws = (char*)d_ws;
    size_t off = 0;
    auto alloc = [&](size_t bytes) -> char* {
        char* p = ws + off;
        off = (off + bytes + 255) & ~(size_t)255;
        return p;
    };

    const int NB = (n + 255) >> 8;
    // partition-path layout
    uint2* recs  = (uint2*)alloc((size_t)ne * sizeof(uint2));
    float* dinv  = (float*)alloc((size_t)n * sizeof(float));
    float* tx1   = (float*)alloc((size_t)n * 2 * sizeof(float));
    float* tx2a  = (float*)alloc((size_t)n * 2 * sizeof(float));
    int*   histS = (int*)alloc((size_t)NBMAX * sizeof(int));
    int*   histD = (int*)alloc((size_t)NBMAX * sizeof(int));
    int*   baseS = (int*)alloc((size_t)NBMAX * sizeof(int));
    int*   baseD = (int*)alloc((size_t)NBMAX * sizeof(int));
    int*   curS  = (int*)alloc((size_t)NBMAX * sizeof(int));
    int*   curD  = (int*)alloc((size_t)NBMAX * sizeof(int));
    const bool partition_ok = (off <= ws_size) && (n <= (1 << 19)) && (NB <= NBMAX);

    if (partition_ok) {
        const int NBLK = (int)((ne + CHUNK - 1) / CHUNK);
        k_zero_ints<<<8, BLK, 0, stream>>>(histS, 2 * NBMAX);  // histS+histD contiguous
        k_hist<<<1024, BLK, 0, stream>>>(srcp, dstp, histS, histD, ne, NB);
        k_scan<<<2, BLK, 0, stream>>>(histS, baseS, curS, histD, baseD, curD, NB);
        k_scatter<0><<<NBLK, BLK, 0, stream>>>(srcp, dstp, w, nullptr, curS, recs, ne, NB);
        k_degdinv<<<NB, BLK, 0, stream>>>(recs, baseS, histS, dinv, n);
        k_scatter<1><<<NBLK, BLK, 0, stream>>>(srcp, dstp, w, dinv, curD, recs, ne, NB);
        k_propb<<<NB, BLK, 0, stream>>>(recs, baseD, histD, (const float2*)x,
                                        (float2*)tx1, n);
        k_propb<<<NB, BLK, 0, stream>>>(recs, baseD, histD, (const float2*)tx1,
                                        (float2*)tx2a, n);
        k_final<<<nblocks, BLK, 0, stream>>>((const float2*)x, (const float2*)tx1,
                                             (const float2*)tx2a,
                                             Wxz, Wxh, bxz, bhz, bxh, bhh,
                                             (float*)d_out, n);
    } else {
        // fallback: global-atomic path (round-2 kernel)
        size_t foff = 0;
        auto falloc = [&](size_t bytes) -> char* {
            char* p = ws + foff;
            foff = (foff + bytes + 255) & ~(size_t)255;
            return p;
        };
        float* deg   = (float*)falloc((size_t)n * sizeof(float));
        float* ftx1  = (float*)falloc((size_t)n * 2 * sizeof(float));
        float* ftx2a = (float*)falloc((size_t)n * 2 * sizeof(float));
        const long long n4 = (long long)(foff / 16);
        k_zero_f4<<<1024, BLK, 0, stream>>>((float4*)ws, n4);
        k_deg_atomic<<<4096, BLK, 0, stream>>>(srcp, dstp, w, deg, ne);
        k_dinv_inplace<<<nblocks, BLK, 0, stream>>>(deg, n);
        k_prop_atomic<<<4096, BLK, 0, stream>>>(srcp, dstp, w, deg,
                                                (const float2*)x, ftx1, ne);
        k_prop_atomic<<<4096, BLK, 0, stream>>>(srcp, dstp, w, deg,
                                                (const float2*)ftx1, ftx2a, ne);
        k_final<<<nblocks, BLK, 0, stream>>>((const float2*)x, (const float2*)ftx1,
                                             (const float2*)ftx2a,
                                             Wxz, Wxh, bxz, bhz, bxh, bhh,
                                             (float*)d_out, n);
    }
}

// Round 4
// 870.678 us; speedup vs baseline: 4.4917x; 1.6273x over previous
//
#include <hip/hip_runtime.h>

// GConvGRU (ChebConv K=3, GRU with H=0) on MI355X.
// H=0 => out = (1 - sigmoid(Cz + bhz)) * tanh(Ch + bhh); Cz/Ch share the
// Chebyshev basis Tx0=x, Tx1=P x, Tx2=2 P Tx1 - x, P = -D^{-1/2} A D^{-1/2}.
//
// Normalization is factored as P v = dinv .* (A^T_w (dinv .* v)) applied in
// epilogues, so edge records store only raw w (self-loops zeroed) and the
// scatter does not depend on deg/dinv -> one merged partition pass builds
// BOTH the src-partition (deg) and dst-partition (prop) record arrays.
// 1024-node buckets give ~256 B contiguous record runs per chunk (low write
// amplification; round-3's 256-node buckets had 4x).

static constexpr int BLK = 256;
static constexpr int BLK_ACC = 512;
static constexpr int NBC_MAX = 512;       // max coarse buckets
static constexpr int BSHIFT = 10;         // 1024 nodes per bucket
static constexpr int BSIZE = 1024;
static constexpr long long CHUNK = 16384; // edges per scatter block

__device__ __forceinline__ void atomAddF(float* p, float v) {
    unsafeAtomicAdd(p, v);
}

// ---------------- utility ----------------

__global__ void k_zero_ints(int* __restrict__ p, int n)
{
    int i = blockIdx.x * blockDim.x + threadIdx.x;
    if (i < n) p[i] = 0;
}

__global__ void k_zero_f4(float4* __restrict__ p, long long n4)
{
    long long i = (long long)blockIdx.x * blockDim.x + threadIdx.x;
    long long stride = (long long)gridDim.x * blockDim.x;
    for (; i < n4; i += stride) p[i] = make_float4(0.f, 0.f, 0.f, 0.f);
}

// ---------------- partition path ----------------

__global__ void k_hist(const int* __restrict__ srcp, const int* __restrict__ dstp,
                       int* __restrict__ histS, int* __restrict__ histD,
                       long long ne, int NB)
{
    __shared__ int lS[NBC_MAX];
    __shared__ int lD[NBC_MAX];
    for (int b = threadIdx.x; b < NB; b += blockDim.x) { lS[b] = 0; lD[b] = 0; }
    __syncthreads();

    const long long ng = (ne + 3) >> 2;
    const long long stride = (long long)gridDim.x * blockDim.x;
    for (long long g = (long long)blockIdx.x * blockDim.x + threadIdx.x; g < ng; g += stride) {
        const long long e = g << 2;
        if (e + 3 < ne) {
            int4 s4 = *(const int4*)(srcp + e);
            int4 d4 = *(const int4*)(dstp + e);
            atomicAdd(&lS[s4.x >> BSHIFT], 1); atomicAdd(&lS[s4.y >> BSHIFT], 1);
            atomicAdd(&lS[s4.z >> BSHIFT], 1); atomicAdd(&lS[s4.w >> BSHIFT], 1);
            atomicAdd(&lD[d4.x >> BSHIFT], 1); atomicAdd(&lD[d4.y >> BSHIFT], 1);
            atomicAdd(&lD[d4.z >> BSHIFT], 1); atomicAdd(&lD[d4.w >> BSHIFT], 1);
        } else {
            for (long long q = e; q < ne; ++q) {
                atomicAdd(&lS[srcp[q] >> BSHIFT], 1);
                atomicAdd(&lD[dstp[q] >> BSHIFT], 1);
            }
        }
    }
    __syncthreads();
    for (int b = threadIdx.x; b < NB; b += blockDim.x) {
        if (lS[b]) atomicAdd(&histS[b], lS[b]);
        if (lD[b]) atomicAdd(&histD[b], lD[b]);
    }
}

// Exclusive scan: block 0 does S, block 1 does D. NB <= 512.
__global__ void k_scan(const int* __restrict__ histS, int* __restrict__ baseS, int* __restrict__ curS,
                       const int* __restrict__ histD, int* __restrict__ baseD, int* __restrict__ curD,
                       int NB)
{
    const int* hist = (blockIdx.x == 0) ? histS : histD;
    int* base = (blockIdx.x == 0) ? baseS : baseD;
    int* cur  = (blockIdx.x == 0) ? curS  : curD;

    __shared__ int part[BLK];
    int t = threadIdx.x;
    int v0 = (2 * t     < NB) ? hist[2 * t]     : 0;
    int v1 = (2 * t + 1 < NB) ? hist[2 * t + 1] : 0;
    part[t] = v0 + v1;
    __syncthreads();
    for (int off = 1; off < BLK; off <<= 1) {
        int val = (t >= off) ? part[t - off] : 0;
        __syncthreads();
        part[t] += val;
        __syncthreads();
    }
    int run = (t == 0) ? 0 : part[t - 1];
    if (2 * t < NB)     { base[2 * t] = run;          cur[2 * t] = run; }
    if (2 * t + 1 < NB) { base[2 * t + 1] = run + v0; cur[2 * t + 1] = run + v0; }
}

// Scatter into per-bucket record arrays. MODE bit0: src-partition (recS),
// bit1: dst-partition (recD). Records store raw w (0 for self-loops).
// recS = { srcLocal(10b), w }; recD = { src(19b) | dstLocal(10b)<<19, w }.
template <int MODE>
__global__ void k_scatter(const int* __restrict__ srcp, const int* __restrict__ dstp,
                          const float* __restrict__ w,
                          int* __restrict__ curS, int* __restrict__ curD,
                          uint2* __restrict__ recS, uint2* __restrict__ recD,
                          long long ne, int NB)
{
    __shared__ int lcS[NBC_MAX];
    __shared__ int lrS[NBC_MAX];
    __shared__ int lcD[NBC_MAX];
    __shared__ int lrD[NBC_MAX];
    const long long cs = (long long)blockIdx.x * CHUNK;
    const long long ce = (cs + CHUNK < ne) ? cs + CHUNK : ne;
    if (cs >= ne) return;

    for (int b = threadIdx.x; b < NB; b += blockDim.x) {
        if (MODE & 1) lcS[b] = 0;
        if (MODE & 2) lcD[b] = 0;
    }
    __syncthreads();

    // pass 1: per-chunk histogram
    for (long long i = cs + (long long)threadIdx.x * 4; i < ce; i += (long long)blockDim.x * 4) {
        if (i + 3 < ce) {
            if (MODE & 1) {
                int4 s4 = *(const int4*)(srcp + i);
                atomicAdd(&lcS[s4.x >> BSHIFT], 1); atomicAdd(&lcS[s4.y >> BSHIFT], 1);
                atomicAdd(&lcS[s4.z >> BSHIFT], 1); atomicAdd(&lcS[s4.w >> BSHIFT], 1);
            }
            if (MODE & 2) {
                int4 d4 = *(const int4*)(dstp + i);
                atomicAdd(&lcD[d4.x >> BSHIFT], 1); atomicAdd(&lcD[d4.y >> BSHIFT], 1);
                atomicAdd(&lcD[d4.z >> BSHIFT], 1); atomicAdd(&lcD[d4.w >> BSHIFT], 1);
            }
        } else {
            for (long long q = i; q < ce; ++q) {
                if (MODE & 1) atomicAdd(&lcS[srcp[q] >> BSHIFT], 1);
                if (MODE & 2) atomicAdd(&lcD[dstp[q] >> BSHIFT], 1);
            }
        }
    }
    __syncthreads();
    // reserve contiguous per-bucket space
    for (int b = threadIdx.x; b < NB; b += blockDim.x) {
        if (MODE & 1) { int c = lcS[b]; lcS[b] = c ? atomicAdd(&curS[b], c) : 0; lrS[b] = 0; }
        if (MODE & 2) { int c = lcD[b]; lcD[b] = c ? atomicAdd(&curD[b], c) : 0; lrD[b] = 0; }
    }
    __syncthreads();
    // pass 2: rank + write records
    for (long long i = cs + (long long)threadIdx.x * 4; i < ce; i += (long long)blockDim.x * 4) {
        if (i + 3 < ce) {
            int4 s4 = *(const int4*)(srcp + i);
            int4 d4 = *(const int4*)(dstp + i);
            float4 w4 = *(const float4*)(w + i);
            int ss[4] = {s4.x, s4.y, s4.z, s4.w};
            int dd[4] = {d4.x, d4.y, d4.z, d4.w};
            float wv[4] = {w4.x, w4.y, w4.z, w4.w};
#pragma unroll
            for (int j = 0; j < 4; ++j) {
                float we = (ss[j] == dd[j]) ? 0.0f : wv[j];
                if (MODE & 1) {
                    int b = ss[j] >> BSHIFT;
                    int r = atomicAdd(&lrS[b], 1);
                    recS[(long long)lcS[b] + r] =
                        make_uint2((unsigned)(ss[j] & (BSIZE - 1)), __float_as_uint(we));
                }
                if (MODE & 2) {
                    int b = dd[j] >> BSHIFT;
                    int r = atomicAdd(&lrD[b], 1);
                    recD[(long long)lcD[b] + r] =
                        make_uint2((unsigned)ss[j] | ((unsigned)(dd[j] & (BSIZE - 1)) << 19),
                                   __float_as_uint(we));
                }
            }
        } else {
            for (long long q = i; q < ce; ++q) {
                int s = srcp[q], d = dstp[q];
                float we = (s == d) ? 0.0f : w[q];
                if (MODE & 1) {
                    int b = s >> BSHIFT;
                    int r = atomicAdd(&lrS[b], 1);
                    recS[(long long)lcS[b] + r] =
                        make_uint2((unsigned)(s & (BSIZE - 1)), __float_as_uint(we));
                }
                if (MODE & 2) {
                    int b = d >> BSHIFT;
                    int r = atomicAdd(&lrD[b], 1);
                    recD[(long long)lcD[b] + r] =
                        make_uint2((unsigned)s | ((unsigned)(d & (BSIZE - 1)) << 19),
                                   __float_as_uint(we));
                }
            }
        }
    }
}

// Per-bucket deg accumulation; epilogue writes dinv and y0 = dinv * x.
__global__ void k_degacc(const uint2* __restrict__ recs, const int* __restrict__ base,
                         const int* __restrict__ hist, const float2* __restrict__ x,
                         float* __restrict__ dinv, float2* __restrict__ y0, int n)
{
    __shared__ float lacc[BSIZE];
    const int b = blockIdx.x;
    for (int i = threadIdx.x; i < BSIZE; i += blockDim.x) lacc[i] = 0.0f;
    __syncthreads();
    const int st = base[b], cnt = hist[b];
    for (int r = threadIdx.x; r < cnt; r += blockDim.x) {
        uint2 rec = recs[(long long)st + r];
        atomicAdd(&lacc[rec.x], __uint_as_float(rec.y));
    }
    __syncthreads();
    for (int i = threadIdx.x; i < BSIZE; i += blockDim.x) {
        int node = (b << BSHIFT) + i;
        if (node < n) {
            float dg = lacc[i];
            float di = (dg > 0.0f) ? rsqrtf(dg) : 0.0f;
            dinv[node] = di;
            float2 xv = x[node];
            y0[node] = make_float2(di * xv.x, di * xv.y);
        }
    }
}

// Per-bucket propagation: raw[d] = sum w * yin[src]; epilogue applies
// out = -dinv[d] * raw  (and optionally yout = dinv[d] * out).
__global__ void k_propc(const uint2* __restrict__ recs, const int* __restrict__ base,
                        const int* __restrict__ hist, const float2* __restrict__ yin,
                        const float* __restrict__ dinv,
                        float2* __restrict__ out, float2* __restrict__ yout, int n)
{
    __shared__ float lax[BSIZE];
    __shared__ float lay[BSIZE];
    const int b = blockIdx.x;
    for (int i = threadIdx.x; i < BSIZE; i += blockDim.x) { lax[i] = 0.0f; lay[i] = 0.0f; }
    __syncthreads();
    const int st = base[b], cnt = hist[b];
    for (int r = threadIdx.x; r < cnt; r += blockDim.x) {
        uint2 rec = recs[(long long)st + r];
        int s  = (int)(rec.x & 0x7FFFFu);
        int dl = (int)(rec.x >> 19);
        float wv = __uint_as_float(rec.y);
        float2 yv = yin[s];
        atomicAdd(&lax[dl], wv * yv.x);
        atomicAdd(&lay[dl], wv * yv.y);
    }
    __syncthreads();
    for (int i = threadIdx.x; i < BSIZE; i += blockDim.x) {
        int node = (b << BSHIFT) + i;
        if (node < n) {
            float di = dinv[node];
            float ox = -di * lax[i];
            float oy = -di * lay[i];
            out[node] = make_float2(ox, oy);
            if (yout) yout[node] = make_float2(di * ox, di * oy);
        }
    }
}

// ---------------- fallback path (global atomics) ----------------

__global__ void k_deg_atomic(const int* __restrict__ srcp, const int* __restrict__ dstp,
                             const float* __restrict__ w, float* __restrict__ deg,
                             long long ne)
{
    const long long ng = (ne + 3) >> 2;
    const long long stride = (long long)gridDim.x * blockDim.x;
    for (long long g = (long long)blockIdx.x * blockDim.x + threadIdx.x; g < ng; g += stride) {
        const long long e = g << 2;
        if (e + 3 < ne) {
            int4 s4 = *(const int4*)(srcp + e);
            int4 d4 = *(const int4*)(dstp + e);
            float4 w4 = *(const float4*)(w + e);
            if (s4.x != d4.x) atomAddF(&deg[s4.x], w4.x);
            if (s4.y != d4.y) atomAddF(&deg[s4.y], w4.y);
            if (s4.z != d4.z) atomAddF(&deg[s4.z], w4.z);
            if (s4.w != d4.w) atomAddF(&deg[s4.w], w4.w);
        } else {
            for (long long q = e; q < ne; ++q) {
                int s = srcp[q], d = dstp[q];
                if (s != d) atomAddF(&deg[s], w[q]);
            }
        }
    }
}

__global__ void k_dinv_inplace(float* __restrict__ deg, int n)
{
    int i = blockIdx.x * blockDim.x + threadIdx.x;
    if (i < n) {
        float d = deg[i];
        deg[i] = (d > 0.0f) ? rsqrtf(d) : 0.0f;
    }
}

__global__ void k_prop_atomic(const int* __restrict__ srcp, const int* __restrict__ dstp,
                              const float* __restrict__ w, const float* __restrict__ dinv,
                              const float2* __restrict__ xin, float* __restrict__ acc,
                              long long ne)
{
    const long long ng = (ne + 3) >> 2;
    const long long stride = (long long)gridDim.x * blockDim.x;
    for (long long g = (long long)blockIdx.x * blockDim.x + threadIdx.x; g < ng; g += stride) {
        const long long e = g << 2;
        if (e + 3 < ne) {
            int4 s4 = *(const int4*)(srcp + e);
            int4 d4 = *(const int4*)(dstp + e);
            float4 w4 = *(const float4*)(w + e);
            int s[4] = {s4.x, s4.y, s4.z, s4.w};
            int d[4] = {d4.x, d4.y, d4.z, d4.w};
            float wv[4] = {w4.x, w4.y, w4.z, w4.w};
#pragma unroll
            for (int j = 0; j < 4; ++j) {
                float wn = (s[j] != d[j]) ? -(dinv[s[j]] * wv[j] * dinv[d[j]]) : 0.0f;
                float2 xv = xin[s[j]];
                atomAddF(&acc[2 * d[j] + 0], wn * xv.x);
                atomAddF(&acc[2 * d[j] + 1], wn * xv.y);
            }
        } else {
            for (long long q = e; q < ne; ++q) {
                int ss = srcp[q], dd = dstp[q];
                float wn = (ss != dd) ? -(dinv[ss] * w[q] * dinv[dd]) : 0.0f;
                float2 xv = xin[ss];
                atomAddF(&acc[2 * dd + 0], wn * xv.x);
                atomAddF(&acc[2 * dd + 1], wn * xv.y);
            }
        }
    }
}

// ---------------- gate epilogue ----------------

__global__ void k_final(const float2* __restrict__ x, const float2* __restrict__ tx1,
                        const float2* __restrict__ tx2a,
                        const float* __restrict__ Wxz, const float* __restrict__ Wxh,
                        const float* __restrict__ bxz, const float* __restrict__ bhz,
                        const float* __restrict__ bxh, const float* __restrict__ bhh,
                        float* __restrict__ out, int n)
{
    int i = blockIdx.x * blockDim.x + threadIdx.x;
    if (i >= n) return;
    float2 t0 = x[i];
    float2 t1 = tx1[i];
    float2 ta = tx2a[i];   // = P(Tx1)
    float t2x = 2.0f * ta.x - t0.x;
    float t2y = 2.0f * ta.y - t0.y;
    float z = t0.x * Wxz[0] + t0.y * Wxz[1]
            + t1.x * Wxz[2] + t1.y * Wxz[3]
            + t2x  * Wxz[4] + t2y  * Wxz[5] + bxz[0] + bhz[0];
    float h = t0.x * Wxh[0] + t0.y * Wxh[1]
            + t1.x * Wxh[2] + t1.y * Wxh[3]
            + t2x  * Wxh[4] + t2y  * Wxh[5] + bxh[0] + bhh[0];
    float zs = 1.0f / (1.0f + expf(-z));
    float ht = tanhf(h);
    out[i] = (1.0f - zs) * ht;
}

// ---------------- launch ----------------

extern "C" void kernel_launch(void* const* d_in, const int* in_sizes, int n_in,
                              void* d_out, int out_size, void* d_ws, size_t ws_size,
                              hipStream_t stream)
{
    const float* x   = (const float*)d_in[0];
    const int*   ei  = (const int*)d_in[1];
    const float* w   = (const float*)d_in[2];
    const float* Wxz = (const float*)d_in[3];
    const float* Wxh = (const float*)d_in[5];
    const float* bxz = (const float*)d_in[9];
    const float* bhz = (const float*)d_in[10];
    const float* bxh = (const float*)d_in[13];
    const float* bhh = (const float*)d_in[14];

    const int n = in_sizes[0] / 2;
    const long long ne = in_sizes[2];
    const int* srcp = ei;
    const int* dstp = ei + ne;
    const int nblocks = (n + BLK - 1) / BLK;
    const int NBC = (n + BSIZE - 1) >> BSHIFT;
    const int NCH = (int)((ne + CHUNK - 1) / CHUNK);

    char* ws = (char*)d_ws;
    size_t off = 0;
    auto alloc = [&](size_t bytes) -> char* {
        char* p = ws + off;
        off = (off + bytes + 255) & ~(size_t)255;
        return p;
    };

    // Layout (path A = two record buffers; path B = one, reused):
    uint2* recD = (uint2*)alloc((size_t)ne * sizeof(uint2));
    const size_t off_after_recD = off;
    uint2* recS = (uint2*)alloc((size_t)ne * sizeof(uint2));   // A only
    const size_t recS_extra = off - off_after_recD;
    float*  dinv = (float*)alloc((size_t)n * sizeof(float));
    float2* y0   = (float2*)alloc((size_t)n * sizeof(float2)); // also tx2a (y0 dead after prop1)
    float2* y1   = (float2*)alloc((size_t)n * sizeof(float2));
    float2* tx1  = (float2*)alloc((size_t)n * sizeof(float2));
    int* histS = (int*)alloc(NBC_MAX * sizeof(int));
    int* histD = (int*)alloc(NBC_MAX * sizeof(int));
    int* baseS = (int*)alloc(NBC_MAX * sizeof(int));
    int* baseD = (int*)alloc(NBC_MAX * sizeof(int));
    int* curS  = (int*)alloc(NBC_MAX * sizeof(int));
    int* curD  = (int*)alloc(NBC_MAX * sizeof(int));
    const size_t need_A = off;
    const size_t need_B = off - recS_extra;
    float2* tx2a = y0;

    const bool nodes_ok = (n <= (1 << 19)) && (NBC <= NBC_MAX);
    const bool pathA = nodes_ok && (need_A <= ws_size);
    const bool pathB = nodes_ok && !pathA && (need_B <= ws_size);

    if (pathA || pathB) {
        if (pathB) {
            // shift everything after recS down by recS_extra
            recS = recD;
            dinv = (float*)((char*)dinv - recS_extra);
            y0   = (float2*)((char*)y0 - recS_extra);
            y1   = (float2*)((char*)y1 - recS_extra);
            tx1  = (float2*)((char*)tx1 - recS_extra);
            histS = (int*)((char*)histS - recS_extra);
            histD = (int*)((char*)histD - recS_extra);
            baseS = (int*)((char*)baseS - recS_extra);
            baseD = (int*)((char*)baseD - recS_extra);
            curS  = (int*)((char*)curS - recS_extra);
            curD  = (int*)((char*)curD - recS_extra);
            tx2a = y0;
        }
        k_zero_ints<<<(2 * NBC_MAX + BLK - 1) / BLK, BLK, 0, stream>>>(histS, 2 * NBC_MAX);
        k_hist<<<1024, BLK, 0, stream>>>(srcp, dstp, histS, histD, ne, NBC);
        k_scan<<<2, BLK, 0, stream>>>(histS, baseS, curS, histD, baseD, curD, NBC);
        if (pathA) {
            k_scatter<3><<<NCH, BLK, 0, stream>>>(srcp, dstp, w, curS, curD,
                                                  recS, recD, ne, NBC);
            k_degacc<<<NBC, BLK_ACC, 0, stream>>>(recS, baseS, histS, (const float2*)x,
                                                  dinv, y0, n);
        } else {
            k_scatter<1><<<NCH, BLK, 0, stream>>>(srcp, dstp, w, curS, curD,
                                                  recS, recD, ne, NBC);
            k_degacc<<<NBC, BLK_ACC, 0, stream>>>(recS, baseS, histS, (const float2*)x,
                                                  dinv, y0, n);
            k_scatter<2><<<NCH, BLK, 0, stream>>>(srcp, dstp, w, curS, curD,
                                                  recS, recD, ne, NBC);
        }
        k_propc<<<NBC, BLK_ACC, 0, stream>>>(recD, baseD, histD, y0, dinv, tx1, y1, n);
        k_propc<<<NBC, BLK_ACC, 0, stream>>>(recD, baseD, histD, y1, dinv, tx2a, nullptr, n);
        k_final<<<nblocks, BLK, 0, stream>>>((const float2*)x, tx1, tx2a,
                                             Wxz, Wxh, bxz, bhz, bxh, bhh,
                                             (float*)d_out, n);
    } else {
        // last-resort: global-atomic path
        size_t foff = 0;
        auto falloc = [&](size_t bytes) -> char* {
            char* p = ws + foff;
            foff = (foff + bytes + 255) & ~(size_t)255;
            return p;
        };
        float* deg   = (float*)falloc((size_t)n * sizeof(float));
        float* ftx1  = (float*)falloc((size_t)n * 2 * sizeof(float));
        float* ftx2a = (float*)falloc((size_t)n * 2 * sizeof(float));
        const long long n4 = (long long)(foff / 16);
        k_zero_f4<<<1024, BLK, 0, stream>>>((float4*)ws, n4);
        k_deg_atomic<<<4096, BLK, 0, stream>>>(srcp, dstp, w, deg, ne);
        k_dinv_inplace<<<nblocks, BLK, 0, stream>>>(deg, n);
        k_prop_atomic<<<4096, BLK, 0, stream>>>(srcp, dstp, w, deg,
                                                (const float2*)x, ftx1, ne);
        k_prop_atomic<<<4096, BLK, 0, stream>>>(srcp, dstp, w, deg,
                                                (const float2*)ftx1, ftx2a, ne);
        k_final<<<nblocks, BLK, 0, stream>>>((const float2*)x, (const float2*)ftx1,
                                             (const float2*)ftx2a,
                                             Wxz, Wxh, bxz, bhz, bxh, bhh,
                                             (float*)d_out, n);
    }
}

// Round 5
// 828.885 us; speedup vs baseline: 4.7182x; 1.0504x over previous
//
#include <hip/hip_runtime.h>

// GConvGRU (ChebConv K=3, GRU with H=0) on MI355X.
// H=0 => out = (1 - sigmoid(Cz + bhz)) * tanh(Ch + bhh); Cz/Ch share the
// Chebyshev basis Tx0=x, Tx1=P x, Tx2=2 P Tx1 - x, P = -D^{-1/2} A D^{-1/2}.
// Factorization: P v = -dinv .* (A_w^T (dinv .* v)), so records store raw w.
//
// Round-4 counters: merged scatter WRITE_SIZE 800 MB vs 256 MB ideal (3x):
// per-(chunk,bucket) runs written scattered-in-time -> partial-line evictions.
// Fix: sort each chunk in LDS, then flush bucket-sorted -> sequential line
// fills. Also: SPLIT accumulate (4 blocks/bucket + combine) for parallelism,
// and the gate epilogue fused into the final prop-combine.

static constexpr int BLK = 256;
static constexpr int BLK_ACC = 512;
static constexpr int NBC_MAX = 512;     // max coarse buckets (n <= 2^19)
static constexpr int BSHIFT = 10;       // 1024 nodes/bucket
static constexpr int BSIZE = 1024;
static constexpr int SCH = 8192;        // edges per sort-scatter chunk (64 KB stage)
static constexpr int SPLIT_MAX = 4;

__device__ __forceinline__ void atomAddF(float* p, float v) {
    unsafeAtomicAdd(p, v);
}

// ---------------- utility ----------------

__global__ void k_zero_ints(int* __restrict__ p, int n)
{
    int i = blockIdx.x * blockDim.x + threadIdx.x;
    if (i < n) p[i] = 0;
}

__global__ void k_zero_f4(float4* __restrict__ p, long long n4)
{
    long long i = (long long)blockIdx.x * blockDim.x + threadIdx.x;
    long long stride = (long long)gridDim.x * blockDim.x;
    for (; i < n4; i += stride) p[i] = make_float4(0.f, 0.f, 0.f, 0.f);
}

// ---------------- histogram + scan ----------------

__global__ void k_hist(const int* __restrict__ srcp, const int* __restrict__ dstp,
                       int* __restrict__ histS, int* __restrict__ histD,
                       long long ne, int NB)
{
    __shared__ int lS[NBC_MAX];
    __shared__ int lD[NBC_MAX];
    for (int b = threadIdx.x; b < NB; b += blockDim.x) { lS[b] = 0; lD[b] = 0; }
    __syncthreads();

    const long long ng = (ne + 3) >> 2;
    const long long stride = (long long)gridDim.x * blockDim.x;
    for (long long g = (long long)blockIdx.x * blockDim.x + threadIdx.x; g < ng; g += stride) {
        const long long e = g << 2;
        if (e + 3 < ne) {
            int4 s4 = *(const int4*)(srcp + e);
            int4 d4 = *(const int4*)(dstp + e);
            atomicAdd(&lS[s4.x >> BSHIFT], 1); atomicAdd(&lS[s4.y >> BSHIFT], 1);
            atomicAdd(&lS[s4.z >> BSHIFT], 1); atomicAdd(&lS[s4.w >> BSHIFT], 1);
            atomicAdd(&lD[d4.x >> BSHIFT], 1); atomicAdd(&lD[d4.y >> BSHIFT], 1);
            atomicAdd(&lD[d4.z >> BSHIFT], 1); atomicAdd(&lD[d4.w >> BSHIFT], 1);
        } else {
            for (long long q = e; q < ne; ++q) {
                atomicAdd(&lS[srcp[q] >> BSHIFT], 1);
                atomicAdd(&lD[dstp[q] >> BSHIFT], 1);
            }
        }
    }
    __syncthreads();
    for (int b = threadIdx.x; b < NB; b += blockDim.x) {
        if (lS[b]) atomicAdd(&histS[b], lS[b]);
        if (lD[b]) atomicAdd(&histD[b], lD[b]);
    }
}

// Exclusive scan: block 0 does S, block 1 does D. NB <= 512, BLK=256.
__global__ void k_scan(const int* __restrict__ histS, int* __restrict__ baseS, int* __restrict__ curS,
                       const int* __restrict__ histD, int* __restrict__ baseD, int* __restrict__ curD,
                       int NB)
{
    const int* hist = (blockIdx.x == 0) ? histS : histD;
    int* base = (blockIdx.x == 0) ? baseS : baseD;
    int* cur  = (blockIdx.x == 0) ? curS  : curD;

    __shared__ int part[BLK];
    int t = threadIdx.x;
    int v0 = (2 * t     < NB) ? hist[2 * t]     : 0;
    int v1 = (2 * t + 1 < NB) ? hist[2 * t + 1] : 0;
    part[t] = v0 + v1;
    __syncthreads();
    for (int off = 1; off < BLK; off <<= 1) {
        int val = (t >= off) ? part[t - off] : 0;
        __syncthreads();
        part[t] += val;
        __syncthreads();
    }
    int run = (t == 0) ? 0 : part[t - 1];
    if (2 * t < NB)     { base[2 * t] = run;          cur[2 * t] = run; }
    if (2 * t + 1 < NB) { base[2 * t + 1] = run + v0; cur[2 * t + 1] = run + v0; }
}

// ---------------- LDS-sorted scatter ----------------
// MODE bit0: src-partition -> recS = { srcLocal(10b), w_eff }
// MODE bit1: dst-partition -> recD = { src | dstLocal<<19, w_eff }
// Each block sorts its SCH-edge chunk in LDS, then flushes bucket-contiguous.
template <int MODE>
__global__ __launch_bounds__(BLK)
void k_sortscatter(const int* __restrict__ srcp, const int* __restrict__ dstp,
                   const float* __restrict__ w,
                   int* __restrict__ curS, int* __restrict__ curD,
                   uint2* __restrict__ recS, uint2* __restrict__ recD,
                   long long ne, int NB)
{
    __shared__ uint2 stage[SCH];          // 64 KB
    __shared__ int loff[NBC_MAX + 1];     // counts -> exclusive offsets (+sentinel)
    __shared__ int lrank[NBC_MAX];
    __shared__ int gdelta[NBC_MAX];
    __shared__ int stmp[BLK];

    const long long cs = (long long)blockIdx.x * SCH;
    if (cs >= ne) return;
    const int cnt_chunk = (int)(((cs + SCH) < ne) ? SCH : (ne - cs));
    const int t = threadIdx.x;

    for (int phase = 0; phase < 2; ++phase) {
        if (!(MODE & (1 << phase))) continue;
        const int* keys = phase ? dstp : srcp;
        int* cur = phase ? curD : curS;
        uint2* rec = phase ? recD : recS;

        for (int b = t; b < NB; b += BLK) { loff[b] = 0; lrank[b] = 0; }
        __syncthreads();

        // pass 1: count
        for (int i = t * 4; i < cnt_chunk; i += BLK * 4) {
            if (i + 3 < cnt_chunk) {
                int4 k4 = *(const int4*)(keys + cs + i);
                atomicAdd(&loff[k4.x >> BSHIFT], 1); atomicAdd(&loff[k4.y >> BSHIFT], 1);
                atomicAdd(&loff[k4.z >> BSHIFT], 1); atomicAdd(&loff[k4.w >> BSHIFT], 1);
            } else {
                for (int q = i; q < cnt_chunk; ++q)
                    atomicAdd(&loff[keys[cs + q] >> BSHIFT], 1);
            }
        }
        __syncthreads();

        // scan counts -> exclusive offsets; reserve global space; delta = g - off
        int v0 = (2 * t     < NB) ? loff[2 * t]     : 0;
        int v1 = (2 * t + 1 < NB) ? loff[2 * t + 1] : 0;
        stmp[t] = v0 + v1;
        __syncthreads();
        for (int off = 1; off < BLK; off <<= 1) {
            int val = (t >= off) ? stmp[t - off] : 0;
            __syncthreads();
            stmp[t] += val;
            __syncthreads();
        }
        int run = (t == 0) ? 0 : stmp[t - 1];
        if (2 * t < NB) {
            int g = atomicAdd(&cur[2 * t], v0);
            loff[2 * t] = run;
            gdelta[2 * t] = g - run;
        }
        if (2 * t + 1 < NB) {
            int g = atomicAdd(&cur[2 * t + 1], v1);
            loff[2 * t + 1] = run + v0;
            gdelta[2 * t + 1] = g - (run + v0);
        }
        if (t == 0) loff[NB] = cnt_chunk;
        __syncthreads();

        // pass 2: place records into stage, bucket-sorted
        for (int i = t * 4; i < cnt_chunk; i += BLK * 4) {
            if (i + 3 < cnt_chunk) {
                int4 s4 = *(const int4*)(srcp + cs + i);
                int4 d4 = *(const int4*)(dstp + cs + i);
                float4 w4 = *(const float4*)(w + cs + i);
                int ss[4] = {s4.x, s4.y, s4.z, s4.w};
                int dd[4] = {d4.x, d4.y, d4.z, d4.w};
                float wv[4] = {w4.x, w4.y, w4.z, w4.w};
#pragma unroll
                for (int j = 0; j < 4; ++j) {
                    float we = (ss[j] == dd[j]) ? 0.0f : wv[j];
                    int key = phase ? dd[j] : ss[j];
                    int b = key >> BSHIFT;
                    int r = atomicAdd(&lrank[b], 1);
                    unsigned meta = phase
                        ? ((unsigned)ss[j] | ((unsigned)(dd[j] & (BSIZE - 1)) << 19))
                        : (unsigned)(ss[j] & (BSIZE - 1));
                    stage[loff[b] + r] = make_uint2(meta, __float_as_uint(we));
                }
            } else {
                for (int q = i; q < cnt_chunk; ++q) {
                    int s = srcp[cs + q], d = dstp[cs + q];
                    float we = (s == d) ? 0.0f : w[cs + q];
                    int key = phase ? d : s;
                    int b = key >> BSHIFT;
                    int r = atomicAdd(&lrank[b], 1);
                    unsigned meta = phase
                        ? ((unsigned)s | ((unsigned)(d & (BSIZE - 1)) << 19))
                        : (unsigned)(s & (BSIZE - 1));
                    stage[loff[b] + r] = make_uint2(meta, __float_as_uint(we));
                }
            }
        }
        __syncthreads();

        // pass 3: flush sorted stage to global (runs are time-contiguous)
        for (int i = t; i < cnt_chunk; i += BLK) {
            int lo = 0, hi = NB;                 // find b: loff[b] <= i < loff[b+1]
            while (hi - lo > 1) {
                int mid = (lo + hi) >> 1;
                if (loff[mid] <= i) lo = mid; else hi = mid;
            }
            rec[(long long)(i + gdelta[lo])] = stage[i];
        }
        __syncthreads();
    }
}

// ---------------- split accumulate + combine ----------------

// deg partial: part[(b*split+sp)*BSIZE + loc] = sum of w for srcLocal==loc.
__global__ __launch_bounds__(BLK_ACC)
void k_degacc(const uint2* __restrict__ recs, const int* __restrict__ base,
              const int* __restrict__ hist, float* __restrict__ part, int split)
{
    __shared__ float lacc[BSIZE];
    const int b = blockIdx.x / split, sp = blockIdx.x % split;
    for (int i = threadIdx.x; i < BSIZE; i += blockDim.x) lacc[i] = 0.0f;
    __syncthreads();
    const int st = base[b], cnt = hist[b];
    const int i0 = (int)((long long)cnt * sp / split);
    const int i1 = (int)((long long)cnt * (sp + 1) / split);
    for (int r = i0 + threadIdx.x; r < i1; r += blockDim.x) {
        uint2 rec = recs[(long long)st + r];
        atomicAdd(&lacc[rec.x & (BSIZE - 1u)], __uint_as_float(rec.y));
    }
    __syncthreads();
    float* dst = part + (size_t)(b * split + sp) * BSIZE;
    for (int i = threadIdx.x; i < BSIZE; i += blockDim.x) dst[i] = lacc[i];
}

// combine deg partials -> dinv, y0 = dinv*x
__global__ void k_degfin(const float* __restrict__ part, const float2* __restrict__ x,
                         float* __restrict__ dinv, float2* __restrict__ y0,
                         int n, int split)
{
    int node = blockIdx.x * blockDim.x + threadIdx.x;
    if (node >= n) return;
    int b = node >> BSHIFT, loc = node & (BSIZE - 1);
    float dg = 0.0f;
    for (int sp = 0; sp < split; ++sp)
        dg += part[(size_t)(b * split + sp) * BSIZE + loc];
    float di = (dg > 0.0f) ? rsqrtf(dg) : 0.0f;
    dinv[node] = di;
    float2 xv = x[node];
    y0[node] = make_float2(di * xv.x, di * xv.y);
}

// prop partial: part[(b*split+sp)*BSIZE + loc] = sum of w * yin[src]
__global__ __launch_bounds__(BLK_ACC)
void k_propacc(const uint2* __restrict__ recs, const int* __restrict__ base,
               const int* __restrict__ hist, const float2* __restrict__ yin,
               float2* __restrict__ part, int split)
{
    __shared__ float lax[BSIZE];
    __shared__ float lay[BSIZE];
    const int b = blockIdx.x / split, sp = blockIdx.x % split;
    for (int i = threadIdx.x; i < BSIZE; i += blockDim.x) { lax[i] = 0.0f; lay[i] = 0.0f; }
    __syncthreads();
    const int st = base[b], cnt = hist[b];
    const int i0 = (int)((long long)cnt * sp / split);
    const int i1 = (int)((long long)cnt * (sp + 1) / split);
    for (int r = i0 + threadIdx.x; r < i1; r += blockDim.x) {
        uint2 rec = recs[(long long)st + r];
        int s  = (int)(rec.x & 0x7FFFFu);
        int dl = (int)(rec.x >> 19);
        float wv = __uint_as_float(rec.y);
        float2 yv = yin[s];
        atomicAdd(&lax[dl], wv * yv.x);
        atomicAdd(&lay[dl], wv * yv.y);
    }
    __syncthreads();
    float2* dst = part + (size_t)(b * split + sp) * BSIZE;
    for (int i = threadIdx.x; i < BSIZE; i += blockDim.x)
        dst[i] = make_float2(lax[i], lay[i]);
}

// combine prop1 partials -> tx1 = -dinv*sum, y1 = dinv*tx1
__global__ void k_propfin1(const float2* __restrict__ part, const float* __restrict__ dinv,
                           float2* __restrict__ tx1, float2* __restrict__ y1,
                           int n, int split)
{
    int node = blockIdx.x * blockDim.x + threadIdx.x;
    if (node >= n) return;
    int b = node >> BSHIFT, loc = node & (BSIZE - 1);
    float sx = 0.0f, sy = 0.0f;
    for (int sp = 0; sp < split; ++sp) {
        float2 v = part[(size_t)(b * split + sp) * BSIZE + loc];
        sx += v.x; sy += v.y;
    }
    float di = dinv[node];
    float ox = -di * sx, oy = -di * sy;
    tx1[node] = make_float2(ox, oy);
    y1[node] = make_float2(di * ox, di * oy);
}

// combine prop2 partials + fused gates -> out
__global__ void k_propfin2(const float2* __restrict__ part, const float* __restrict__ dinv,
                           const float2* __restrict__ x, const float2* __restrict__ tx1,
                           const float* __restrict__ Wxz, const float* __restrict__ Wxh,
                           const float* __restrict__ bxz, const float* __restrict__ bhz,
                           const float* __restrict__ bxh, const float* __restrict__ bhh,
                           float* __restrict__ out, int n, int split)
{
    int node = blockIdx.x * blockDim.x + threadIdx.x;
    if (node >= n) return;
    int b = node >> BSHIFT, loc = node & (BSIZE - 1);
    float sx = 0.0f, sy = 0.0f;
    for (int sp = 0; sp < split; ++sp) {
        float2 v = part[(size_t)(b * split + sp) * BSIZE + loc];
        sx += v.x; sy += v.y;
    }
    float di = dinv[node];
    float2 t0 = x[node];
    float2 t1 = tx1[node];
    float t2x = 2.0f * (-di * sx) - t0.x;
    float t2y = 2.0f * (-di * sy) - t0.y;
    float z = t0.x * Wxz[0] + t0.y * Wxz[1]
            + t1.x * Wxz[2] + t1.y * Wxz[3]
            + t2x  * Wxz[4] + t2y  * Wxz[5] + bxz[0] + bhz[0];
    float h = t0.x * Wxh[0] + t0.y * Wxh[1]
            + t1.x * Wxh[2] + t1.y * Wxh[3]
            + t2x  * Wxh[4] + t2y  * Wxh[5] + bxh[0] + bhh[0];
    float zs = 1.0f / (1.0f + expf(-z));
    float ht = tanhf(h);
    out[node] = (1.0f - zs) * ht;
}

// ---------------- atomic fallback ----------------

__global__ void k_deg_atomic(const int* __restrict__ srcp, const int* __restrict__ dstp,
                             const float* __restrict__ w, float* __restrict__ deg,
                             long long ne)
{
    const long long ng = (ne + 3) >> 2;
    const long long stride = (long long)gridDim.x * blockDim.x;
    for (long long g = (long long)blockIdx.x * blockDim.x + threadIdx.x; g < ng; g += stride) {
        const long long e = g << 2;
        if (e + 3 < ne) {
            int4 s4 = *(const int4*)(srcp + e);
            int4 d4 = *(const int4*)(dstp + e);
            float4 w4 = *(const float4*)(w + e);
            if (s4.x != d4.x) atomAddF(&deg[s4.x], w4.x);
            if (s4.y != d4.y) atomAddF(&deg[s4.y], w4.y);
            if (s4.z != d4.z) atomAddF(&deg[s4.z], w4.z);
            if (s4.w != d4.w) atomAddF(&deg[s4.w], w4.w);
        } else {
            for (long long q = e; q < ne; ++q) {
                int s = srcp[q], d = dstp[q];
                if (s != d) atomAddF(&deg[s], w[q]);
            }
        }
    }
}

__global__ void k_dinv_inplace(float* __restrict__ deg, int n)
{
    int i = blockIdx.x * blockDim.x + threadIdx.x;
    if (i < n) {
        float d = deg[i];
        deg[i] = (d > 0.0f) ? rsqrtf(d) : 0.0f;
    }
}

__global__ void k_prop_atomic(const int* __restrict__ srcp, const int* __restrict__ dstp,
                              const float* __restrict__ w, const float* __restrict__ dinv,
                              const float2* __restrict__ xin, float* __restrict__ acc,
                              long long ne)
{
    const long long ng = (ne + 3) >> 2;
    const long long stride = (long long)gridDim.x * blockDim.x;
    for (long long g = (long long)blockIdx.x * blockDim.x + threadIdx.x; g < ng; g += stride) {
        const long long e = g << 2;
        if (e + 3 < ne) {
            int4 s4 = *(const int4*)(srcp + e);
            int4 d4 = *(const int4*)(dstp + e);
            float4 w4 = *(const float4*)(w + e);
            int s[4] = {s4.x, s4.y, s4.z, s4.w};
            int d[4] = {d4.x, d4.y, d4.z, d4.w};
            float wv[4] = {w4.x, w4.y, w4.z, w4.w};
#pragma unroll
            for (int j = 0; j < 4; ++j) {
                float wn = (s[j] != d[j]) ? -(dinv[s[j]] * wv[j] * dinv[d[j]]) : 0.0f;
                float2 xv = xin[s[j]];
                atomAddF(&acc[2 * d[j] + 0], wn * xv.x);
                atomAddF(&acc[2 * d[j] + 1], wn * xv.y);
            }
        } else {
            for (long long q = e; q < ne; ++q) {
                int ss = srcp[q], dd = dstp[q];
                float wn = (ss != dd) ? -(dinv[ss] * w[q] * dinv[dd]) : 0.0f;
                float2 xv = xin[ss];
                atomAddF(&acc[2 * dd + 0], wn * xv.x);
                atomAddF(&acc[2 * dd + 1], wn * xv.y);
            }
        }
    }
}

__global__ void k_final(const float2* __restrict__ x, const float2* __restrict__ tx1,
                        const float2* __restrict__ tx2a,
                        const float* __restrict__ Wxz, const float* __restrict__ Wxh,
                        const float* __restrict__ bxz, const float* __restrict__ bhz,
                        const float* __restrict__ bxh, const float* __restrict__ bhh,
                        float* __restrict__ out, int n)
{
    int i = blockIdx.x * blockDim.x + threadIdx.x;
    if (i >= n) return;
    float2 t0 = x[i];
    float2 t1 = tx1[i];
    float2 ta = tx2a[i];
    float t2x = 2.0f * ta.x - t0.x;
    float t2y = 2.0f * ta.y - t0.y;
    float z = t0.x * Wxz[0] + t0.y * Wxz[1]
            + t1.x * Wxz[2] + t1.y * Wxz[3]
            + t2x  * Wxz[4] + t2y  * Wxz[5] + bxz[0] + bhz[0];
    float h = t0.x * Wxh[0] + t0.y * Wxh[1]
            + t1.x * Wxh[2] + t1.y * Wxh[3]
            + t2x  * Wxh[4] + t2y  * Wxh[5] + bxh[0] + bhh[0];
    float zs = 1.0f / (1.0f + expf(-z));
    float ht = tanhf(h);
    out[i] = (1.0f - zs) * ht;
}

// ---------------- launch ----------------

struct Lay {
    uint2 *recD, *recS;
    float* dinv;
    float2 *y0, *y1, *tx1;
    float* part;               // SPLIT partials (deg uses as float, prop as float2)
    int *histS, *histD, *baseS, *baseD, *curS, *curD;
    size_t need;
};

static Lay make_layout(char* ws, long long ne, int n, int NBC, bool two_rec, int split)
{
    Lay L{};
    size_t off = 0;
    auto alloc = [&](size_t bytes) -> char* {
        char* p = ws + off;
        off = (off + bytes + 255) & ~(size_t)255;
        return p;
    };
    L.recD = (uint2*)alloc((size_t)ne * sizeof(uint2));
    L.recS = two_rec ? (uint2*)alloc((size_t)ne * sizeof(uint2)) : L.recD;
    L.dinv = (float*)alloc((size_t)n * sizeof(float));
    L.y0   = (float2*)alloc((size_t)n * sizeof(float2));
    L.y1   = (float2*)alloc((size_t)n * sizeof(float2));
    L.tx1  = (float2*)alloc((size_t)n * sizeof(float2));
    L.part = (float*)alloc((size_t)NBC * split * BSIZE * sizeof(float2));
    L.histS = (int*)alloc(NBC_MAX * sizeof(int));
    L.histD = (int*)alloc(NBC_MAX * sizeof(int));
    L.baseS = (int*)alloc(NBC_MAX * sizeof(int));
    L.baseD = (int*)alloc(NBC_MAX * sizeof(int));
    L.curS  = (int*)alloc(NBC_MAX * sizeof(int));
    L.curD  = (int*)alloc(NBC_MAX * sizeof(int));
    L.need = off;
    return L;
}

extern "C" void kernel_launch(void* const* d_in, const int* in_sizes, int n_in,
                              void* d_out, int out_size, void* d_ws, size_t ws_size,
                              hipStream_t stream)
{
    const float* x   = (const float*)d_in[0];
    const int*   ei  = (const int*)d_in[1];
    const float* w   = (const float*)d_in[2];
    const float* Wxz = (const float*)d_in[3];
    const float* Wxh = (const float*)d_in[5];
    const float* bxz = (const float*)d_in[9];
    const float* bhz = (const float*)d_in[10];
    const float* bxh = (const float*)d_in[13];
    const float* bhh = (const float*)d_in[14];

    const int n = in_sizes[0] / 2;
    const long long ne = in_sizes[2];
    const int* srcp = ei;
    const int* dstp = ei + ne;
    const int nblocks = (n + BLK - 1) / BLK;
    const int NBC = (n + BSIZE - 1) >> BSHIFT;
    const int NCH = (int)((ne + SCH - 1) / SCH);
    char* ws = (char*)d_ws;

    const bool nodes_ok = (n <= (1 << 19)) && (NBC <= NBC_MAX);

    // choose config: A4 (two recs, split4) > A1 > B4 (one rec, split4) > atomic
    bool two_rec = true;
    int split = SPLIT_MAX;
    Lay L = make_layout(ws, ne, n, NBC, true, SPLIT_MAX);
    bool ok = nodes_ok && L.need <= ws_size;
    if (nodes_ok && !ok) {
        L = make_layout(ws, ne, n, NBC, true, 1); split = 1;
        ok = L.need <= ws_size;
    }
    if (nodes_ok && !ok) {
        L = make_layout(ws, ne, n, NBC, false, SPLIT_MAX); two_rec = false; split = SPLIT_MAX;
        ok = L.need <= ws_size;
    }

    if (ok) {
        k_zero_ints<<<(2 * NBC_MAX + BLK - 1) / BLK, BLK, 0, stream>>>(L.histS, 2 * NBC_MAX);
        k_hist<<<1024, BLK, 0, stream>>>(srcp, dstp, L.histS, L.histD, ne, NBC);
        k_scan<<<2, BLK, 0, stream>>>(L.histS, L.baseS, L.curS, L.histD, L.baseD, L.curD, NBC);
        if (two_rec) {
            k_sortscatter<3><<<NCH, BLK, 0, stream>>>(srcp, dstp, w, L.curS, L.curD,
                                                      L.recS, L.recD, ne, NBC);
            k_degacc<<<NBC * split, BLK_ACC, 0, stream>>>(L.recS, L.baseS, L.histS,
                                                          L.part, split);
            k_degfin<<<nblocks, BLK, 0, stream>>>(L.part, (const float2*)x,
                                                  L.dinv, L.y0, n, split);
        } else {
            k_sortscatter<1><<<NCH, BLK, 0, stream>>>(srcp, dstp, w, L.curS, L.curD,
                                                      L.recS, L.recD, ne, NBC);
            k_degacc<<<NBC * split, BLK_ACC, 0, stream>>>(L.recS, L.baseS, L.histS,
                                                          L.part, split);
            k_degfin<<<nblocks, BLK, 0, stream>>>(L.part, (const float2*)x,
                                                  L.dinv, L.y0, n, split);
            k_sortscatter<2><<<NCH, BLK, 0, stream>>>(srcp, dstp, w, L.curS, L.curD,
                                                      L.recS, L.recD, ne, NBC);
        }
        k_propacc<<<NBC * split, BLK_ACC, 0, stream>>>(L.recD, L.baseD, L.histD,
                                                       L.y0, (float2*)L.part, split);
        k_propfin1<<<nblocks, BLK, 0, stream>>>((const float2*)L.part, L.dinv,
                                                L.tx1, L.y1, n, split);
        k_propacc<<<NBC * split, BLK_ACC, 0, stream>>>(L.recD, L.baseD, L.histD,
                                                       L.y1, (float2*)L.part, split);
        k_propfin2<<<nblocks, BLK, 0, stream>>>((const float2*)L.part, L.dinv,
                                                (const float2*)x, L.tx1,
                                                Wxz, Wxh, bxz, bhz, bxh, bhh,
                                                (float*)d_out, n, split);
    } else {
        // last-resort: global-atomic path
        size_t foff = 0;
        auto falloc = [&](size_t bytes) -> char* {
            char* p = ws + foff;
            foff = (foff + bytes + 255) & ~(size_t)255;
            return p;
        };
        float* deg   = (float*)falloc((size_t)n * sizeof(float));
        float* ftx1  = (float*)falloc((size_t)n * 2 * sizeof(float));
        float* ftx2a = (float*)falloc((size_t)n * 2 * sizeof(float));
        const long long n4 = (long long)(foff / 16);
        k_zero_f4<<<1024, BLK, 0, stream>>>((float4*)ws, n4);
        k_deg_atomic<<<4096, BLK, 0, stream>>>(srcp, dstp, w, deg, ne);
        k_dinv_inplace<<<nblocks, BLK, 0, stream>>>(deg, n);
        k_prop_atomic<<<4096, BLK, 0, stream>>>(srcp, dstp, w, deg,
                                                (const float2*)x, ftx1, ne);
        k_prop_atomic<<<4096, BLK, 0, stream>>>(srcp, dstp, w, deg,
                                                (const float2*)ftx1, ftx2a, ne);
        k_final<<<nblocks, BLK, 0, stream>>>((const float2*)x, (const float2*)ftx1,
                                             (const float2*)ftx2a,
                                             Wxz, Wxh, bxz, bhz, bxh, bhh,
                                             (float*)d_out, n);
    }
}

// Round 6
// 777.226 us; speedup vs baseline: 5.0318x; 1.0665x over previous
//
#include <hip/hip_runtime.h>

// GConvGRU (ChebConv K=3, GRU with H=0) on MI355X.
// H=0 => out = (1 - sigmoid(Cz + bhz)) * tanh(Ch + bhh); Cz/Ch share the
// Chebyshev basis Tx0=x, Tx1=P x, Tx2=2 P Tx1 - x, P = -D^{-1/2} A D^{-1/2}.
// Factorization: P v = -dinv .* (A_w^T (dinv .* v)), so records store raw w.
//
// Round-5 counters: sortscatter latency/occupancy-bound (Occ 21.7%, VALU 24%,
// 11.7M LDS-conflict cycles). Fixes: SCH 4096 (48 KB LDS -> 3 blocks/CU),
// slotbkt ushort array replaces 9-step binary search in flush, XCD-bijective
// chunk swizzle so adjacent bucket-run appends share an XCD L2, split 4->8.

static constexpr int BLK = 256;
static constexpr int BLK_ACC = 512;
static constexpr int NBC_MAX = 512;     // max coarse buckets (n <= 2^19)
static constexpr int BSHIFT = 10;       // 1024 nodes/bucket
static constexpr int BSIZE = 1024;
static constexpr int SCH = 4096;        // edges per sort-scatter chunk (32 KB stage)

__device__ __forceinline__ void atomAddF(float* p, float v) {
    unsafeAtomicAdd(p, v);
}

// ---------------- utility ----------------

__global__ void k_zero_ints(int* __restrict__ p, int n)
{
    int i = blockIdx.x * blockDim.x + threadIdx.x;
    if (i < n) p[i] = 0;
}

__global__ void k_zero_f4(float4* __restrict__ p, long long n4)
{
    long long i = (long long)blockIdx.x * blockDim.x + threadIdx.x;
    long long stride = (long long)gridDim.x * blockDim.x;
    for (; i < n4; i += stride) p[i] = make_float4(0.f, 0.f, 0.f, 0.f);
}

// ---------------- histogram + scan ----------------

__global__ void k_hist(const int* __restrict__ srcp, const int* __restrict__ dstp,
                       int* __restrict__ histS, int* __restrict__ histD,
                       long long ne, int NB)
{
    __shared__ int lS[NBC_MAX];
    __shared__ int lD[NBC_MAX];
    for (int b = threadIdx.x; b < NB; b += blockDim.x) { lS[b] = 0; lD[b] = 0; }
    __syncthreads();

    const long long ng = (ne + 3) >> 2;
    const long long stride = (long long)gridDim.x * blockDim.x;
    for (long long g = (long long)blockIdx.x * blockDim.x + threadIdx.x; g < ng; g += stride) {
        const long long e = g << 2;
        if (e + 3 < ne) {
            int4 s4 = *(const int4*)(srcp + e);
            int4 d4 = *(const int4*)(dstp + e);
            atomicAdd(&lS[s4.x >> BSHIFT], 1); atomicAdd(&lS[s4.y >> BSHIFT], 1);
            atomicAdd(&lS[s4.z >> BSHIFT], 1); atomicAdd(&lS[s4.w >> BSHIFT], 1);
            atomicAdd(&lD[d4.x >> BSHIFT], 1); atomicAdd(&lD[d4.y >> BSHIFT], 1);
            atomicAdd(&lD[d4.z >> BSHIFT], 1); atomicAdd(&lD[d4.w >> BSHIFT], 1);
        } else {
            for (long long q = e; q < ne; ++q) {
                atomicAdd(&lS[srcp[q] >> BSHIFT], 1);
                atomicAdd(&lD[dstp[q] >> BSHIFT], 1);
            }
        }
    }
    __syncthreads();
    for (int b = threadIdx.x; b < NB; b += blockDim.x) {
        if (lS[b]) atomicAdd(&histS[b], lS[b]);
        if (lD[b]) atomicAdd(&histD[b], lD[b]);
    }
}

// Exclusive scan: block 0 does S, block 1 does D. NB <= 512, BLK=256.
__global__ void k_scan(const int* __restrict__ histS, int* __restrict__ baseS, int* __restrict__ curS,
                       const int* __restrict__ histD, int* __restrict__ baseD, int* __restrict__ curD,
                       int NB)
{
    const int* hist = (blockIdx.x == 0) ? histS : histD;
    int* base = (blockIdx.x == 0) ? baseS : baseD;
    int* cur  = (blockIdx.x == 0) ? curS  : curD;

    __shared__ int part[BLK];
    int t = threadIdx.x;
    int v0 = (2 * t     < NB) ? hist[2 * t]     : 0;
    int v1 = (2 * t + 1 < NB) ? hist[2 * t + 1] : 0;
    part[t] = v0 + v1;
    __syncthreads();
    for (int off = 1; off < BLK; off <<= 1) {
        int val = (t >= off) ? part[t - off] : 0;
        __syncthreads();
        part[t] += val;
        __syncthreads();
    }
    int run = (t == 0) ? 0 : part[t - 1];
    if (2 * t < NB)     { base[2 * t] = run;          cur[2 * t] = run; }
    if (2 * t + 1 < NB) { base[2 * t + 1] = run + v0; cur[2 * t + 1] = run + v0; }
}

// ---------------- LDS-sorted scatter ----------------
// MODE bit0: src-partition -> recS = { srcLocal(10b), w_eff }
// MODE bit1: dst-partition -> recD = { src | dstLocal<<19, w_eff }
// Each block sorts its SCH-edge chunk in LDS, then flushes bucket-contiguous.
// Chunk order is XCD-swizzled (bijective, m204 form) so consecutive chunks
// (adjacent appends in each bucket region) run on the same XCD L2.
template <int MODE>
__global__ __launch_bounds__(BLK)
void k_sortscatter(const int* __restrict__ srcp, const int* __restrict__ dstp,
                   const float* __restrict__ w,
                   int* __restrict__ curS, int* __restrict__ curD,
                   uint2* __restrict__ recS, uint2* __restrict__ recD,
                   long long ne, int NB, int NCH)
{
    __shared__ uint2 stage[SCH];            // 32 KB
    __shared__ unsigned short slotbkt[SCH]; // 8 KB: slot -> bucket
    __shared__ int loff[NBC_MAX];           // counts -> exclusive offsets
    __shared__ int lrank[NBC_MAX];
    __shared__ int gdelta[NBC_MAX];
    __shared__ int stmp[BLK];

    // bijective XCD swizzle: blocks with the same blockIdx%8 (same XCD under
    // round-robin dispatch) process a contiguous range of chunks.
    const int orig = blockIdx.x;
    const int xcd = orig & 7, idx = orig >> 3;
    const int q8 = NCH >> 3, r8 = NCH & 7;
    const int chunk = (xcd < r8 ? xcd * (q8 + 1) : r8 * (q8 + 1) + (xcd - r8) * q8) + idx;

    const long long cs = (long long)chunk * SCH;
    if (cs >= ne) return;
    const int cnt_chunk = (int)(((cs + SCH) < ne) ? SCH : (ne - cs));
    const int t = threadIdx.x;

    for (int phase = 0; phase < 2; ++phase) {
        if (!(MODE & (1 << phase))) continue;
        const int* keys = phase ? dstp : srcp;
        int* cur = phase ? curD : curS;
        uint2* rec = phase ? recD : recS;

        for (int b = t; b < NB; b += BLK) { loff[b] = 0; lrank[b] = 0; }
        __syncthreads();

        // pass 1: count
        for (int i = t * 4; i < cnt_chunk; i += BLK * 4) {
            if (i + 3 < cnt_chunk) {
                int4 k4 = *(const int4*)(keys + cs + i);
                atomicAdd(&loff[k4.x >> BSHIFT], 1); atomicAdd(&loff[k4.y >> BSHIFT], 1);
                atomicAdd(&loff[k4.z >> BSHIFT], 1); atomicAdd(&loff[k4.w >> BSHIFT], 1);
            } else {
                for (int q = i; q < cnt_chunk; ++q)
                    atomicAdd(&loff[keys[cs + q] >> BSHIFT], 1);
            }
        }
        __syncthreads();

        // scan counts -> exclusive offsets; reserve global space; delta = g - off
        int v0 = (2 * t     < NB) ? loff[2 * t]     : 0;
        int v1 = (2 * t + 1 < NB) ? loff[2 * t + 1] : 0;
        stmp[t] = v0 + v1;
        __syncthreads();
        for (int off = 1; off < BLK; off <<= 1) {
            int val = (t >= off) ? stmp[t - off] : 0;
            __syncthreads();
            stmp[t] += val;
            __syncthreads();
        }
        int run = (t == 0) ? 0 : stmp[t - 1];
        if (2 * t < NB) {
            int g = (v0 > 0) ? atomicAdd(&cur[2 * t], v0) : 0;
            loff[2 * t] = run;
            gdelta[2 * t] = g - run;
        }
        if (2 * t + 1 < NB) {
            int g = (v1 > 0) ? atomicAdd(&cur[2 * t + 1], v1) : 0;
            loff[2 * t + 1] = run + v0;
            gdelta[2 * t + 1] = g - (run + v0);
        }
        __syncthreads();

        // pass 2: place records into stage, bucket-sorted; record slot->bucket
        for (int i = t * 4; i < cnt_chunk; i += BLK * 4) {
            if (i + 3 < cnt_chunk) {
                int4 s4 = *(const int4*)(srcp + cs + i);
                int4 d4 = *(const int4*)(dstp + cs + i);
                float4 w4 = *(const float4*)(w + cs + i);
                int ss[4] = {s4.x, s4.y, s4.z, s4.w};
                int dd[4] = {d4.x, d4.y, d4.z, d4.w};
                float wv[4] = {w4.x, w4.y, w4.z, w4.w};
#pragma unroll
                for (int j = 0; j < 4; ++j) {
                    float we = (ss[j] == dd[j]) ? 0.0f : wv[j];
                    int key = phase ? dd[j] : ss[j];
                    int b = key >> BSHIFT;
                    int r = atomicAdd(&lrank[b], 1);
                    unsigned meta = phase
                        ? ((unsigned)ss[j] | ((unsigned)(dd[j] & (BSIZE - 1)) << 19))
                        : (unsigned)(ss[j] & (BSIZE - 1));
                    int pos = loff[b] + r;
                    stage[pos] = make_uint2(meta, __float_as_uint(we));
                    slotbkt[pos] = (unsigned short)b;
                }
            } else {
                for (int q = i; q < cnt_chunk; ++q) {
                    int s = srcp[cs + q], d = dstp[cs + q];
                    float we = (s == d) ? 0.0f : w[cs + q];
                    int key = phase ? d : s;
                    int b = key >> BSHIFT;
                    int r = atomicAdd(&lrank[b], 1);
                    unsigned meta = phase
                        ? ((unsigned)s | ((unsigned)(d & (BSIZE - 1)) << 19))
                        : (unsigned)(s & (BSIZE - 1));
                    int pos = loff[b] + r;
                    stage[pos] = make_uint2(meta, __float_as_uint(we));
                    slotbkt[pos] = (unsigned short)b;
                }
            }
        }
        __syncthreads();

        // pass 3: flush sorted stage (runs are time- and address-contiguous)
        for (int i = t; i < cnt_chunk; i += BLK) {
            int b = slotbkt[i];
            rec[(long long)(i + gdelta[b])] = stage[i];
        }
        __syncthreads();
    }
}

// ---------------- split accumulate + combine ----------------

// deg partial: part[(b*split+sp)*BSIZE + loc] = sum of w for srcLocal==loc.
__global__ __launch_bounds__(BLK_ACC)
void k_degacc(const uint2* __restrict__ recs, const int* __restrict__ base,
              const int* __restrict__ hist, float* __restrict__ part, int split)
{
    __shared__ float lacc[BSIZE];
    const int b = blockIdx.x / split, sp = blockIdx.x % split;
    for (int i = threadIdx.x; i < BSIZE; i += blockDim.x) lacc[i] = 0.0f;
    __syncthreads();
    const int st = base[b], cnt = hist[b];
    const int i0 = (int)((long long)cnt * sp / split);
    const int i1 = (int)((long long)cnt * (sp + 1) / split);
    for (int r = i0 + threadIdx.x; r < i1; r += blockDim.x) {
        uint2 rec = recs[(long long)st + r];
        atomicAdd(&lacc[rec.x & (BSIZE - 1u)], __uint_as_float(rec.y));
    }
    __syncthreads();
    float* dst = part + (size_t)(b * split + sp) * BSIZE;
    for (int i = threadIdx.x; i < BSIZE; i += blockDim.x) dst[i] = lacc[i];
}

// combine deg partials -> dinv, y0 = dinv*x
__global__ void k_degfin(const float* __restrict__ part, const float2* __restrict__ x,
                         float* __restrict__ dinv, float2* __restrict__ y0,
                         int n, int split)
{
    int node = blockIdx.x * blockDim.x + threadIdx.x;
    if (node >= n) return;
    int b = node >> BSHIFT, loc = node & (BSIZE - 1);
    float dg = 0.0f;
    for (int sp = 0; sp < split; ++sp)
        dg += part[(size_t)(b * split + sp) * BSIZE + loc];
    float di = (dg > 0.0f) ? rsqrtf(dg) : 0.0f;
    dinv[node] = di;
    float2 xv = x[node];
    y0[node] = make_float2(di * xv.x, di * xv.y);
}

// prop partial: part[(b*split+sp)*BSIZE + loc] = sum of w * yin[src]
__global__ __launch_bounds__(BLK_ACC)
void k_propacc(const uint2* __restrict__ recs, const int* __restrict__ base,
               const int* __restrict__ hist, const float2* __restrict__ yin,
               float2* __restrict__ part, int split)
{
    __shared__ float lax[BSIZE];
    __shared__ float lay[BSIZE];
    const int b = blockIdx.x / split, sp = blockIdx.x % split;
    for (int i = threadIdx.x; i < BSIZE; i += blockDim.x) { lax[i] = 0.0f; lay[i] = 0.0f; }
    __syncthreads();
    const int st = base[b], cnt = hist[b];
    const int i0 = (int)((long long)cnt * sp / split);
    const int i1 = (int)((long long)cnt * (sp + 1) / split);
    for (int r = i0 + threadIdx.x; r < i1; r += blockDim.x) {
        uint2 rec = recs[(long long)st + r];
        int s  = (int)(rec.x & 0x7FFFFu);
        int dl = (int)(rec.x >> 19);
        float wv = __uint_as_float(rec.y);
        float2 yv = yin[s];
        atomicAdd(&lax[dl], wv * yv.x);
        atomicAdd(&lay[dl], wv * yv.y);
    }
    __syncthreads();
    float2* dst = part + (size_t)(b * split + sp) * BSIZE;
    for (int i = threadIdx.x; i < BSIZE; i += blockDim.x)
        dst[i] = make_float2(lax[i], lay[i]);
}

// combine prop1 partials -> tx1 = -dinv*sum, y1 = dinv*tx1
__global__ void k_propfin1(const float2* __restrict__ part, const float* __restrict__ dinv,
                           float2* __restrict__ tx1, float2* __restrict__ y1,
                           int n, int split)
{
    int node = blockIdx.x * blockDim.x + threadIdx.x;
    if (node >= n) return;
    int b = node >> BSHIFT, loc = node & (BSIZE - 1);
    float sx = 0.0f, sy = 0.0f;
    for (int sp = 0; sp < split; ++sp) {
        float2 v = part[(size_t)(b * split + sp) * BSIZE + loc];
        sx += v.x; sy += v.y;
    }
    float di = dinv[node];
    float ox = -di * sx, oy = -di * sy;
    tx1[node] = make_float2(ox, oy);
    y1[node] = make_float2(di * ox, di * oy);
}

// combine prop2 partials + fused gates -> out
__global__ void k_propfin2(const float2* __restrict__ part, const float* __restrict__ dinv,
                           const float2* __restrict__ x, const float2* __restrict__ tx1,
                           const float* __restrict__ Wxz, const float* __restrict__ Wxh,
                           const float* __restrict__ bxz, const float* __restrict__ bhz,
                           const float* __restrict__ bxh, const float* __restrict__ bhh,
                           float* __restrict__ out, int n, int split)
{
    int node = blockIdx.x * blockDim.x + threadIdx.x;
    if (node >= n) return;
    int b = node >> BSHIFT, loc = node & (BSIZE - 1);
    float sx = 0.0f, sy = 0.0f;
    for (int sp = 0; sp < split; ++sp) {
        float2 v = part[(size_t)(b * split + sp) * BSIZE + loc];
        sx += v.x; sy += v.y;
    }
    float di = dinv[node];
    float2 t0 = x[node];
    float2 t1 = tx1[node];
    float t2x = 2.0f * (-di * sx) - t0.x;
    float t2y = 2.0f * (-di * sy) - t0.y;
    float z = t0.x * Wxz[0] + t0.y * Wxz[1]
            + t1.x * Wxz[2] + t1.y * Wxz[3]
            + t2x  * Wxz[4] + t2y  * Wxz[5] + bxz[0] + bhz[0];
    float h = t0.x * Wxh[0] + t0.y * Wxh[1]
            + t1.x * Wxh[2] + t1.y * Wxh[3]
            + t2x  * Wxh[4] + t2y  * Wxh[5] + bxh[0] + bhh[0];
    float zs = 1.0f / (1.0f + expf(-z));
    float ht = tanhf(h);
    out[node] = (1.0f - zs) * ht;
}

// ---------------- atomic fallback ----------------

__global__ void k_deg_atomic(const int* __restrict__ srcp, const int* __restrict__ dstp,
                             const float* __restrict__ w, float* __restrict__ deg,
                             long long ne)
{
    const long long ng = (ne + 3) >> 2;
    const long long stride = (long long)gridDim.x * blockDim.x;
    for (long long g = (long long)blockIdx.x * blockDim.x + threadIdx.x; g < ng; g += stride) {
        const long long e = g << 2;
        if (e + 3 < ne) {
            int4 s4 = *(const int4*)(srcp + e);
            int4 d4 = *(const int4*)(dstp + e);
            float4 w4 = *(const float4*)(w + e);
            if (s4.x != d4.x) atomAddF(&deg[s4.x], w4.x);
            if (s4.y != d4.y) atomAddF(&deg[s4.y], w4.y);
            if (s4.z != d4.z) atomAddF(&deg[s4.z], w4.z);
            if (s4.w != d4.w) atomAddF(&deg[s4.w], w4.w);
        } else {
            for (long long q = e; q < ne; ++q) {
                int s = srcp[q], d = dstp[q];
                if (s != d) atomAddF(&deg[s], w[q]);
            }
        }
    }
}

__global__ void k_dinv_inplace(float* __restrict__ deg, int n)
{
    int i = blockIdx.x * blockDim.x + threadIdx.x;
    if (i < n) {
        float d = deg[i];
        deg[i] = (d > 0.0f) ? rsqrtf(d) : 0.0f;
    }
}

__global__ void k_prop_atomic(const int* __restrict__ srcp, const int* __restrict__ dstp,
                              const float* __restrict__ w, const float* __restrict__ dinv,
                              const float2* __restrict__ xin, float* __restrict__ acc,
                              long long ne)
{
    const long long ng = (ne + 3) >> 2;
    const long long stride = (long long)gridDim.x * blockDim.x;
    for (long long g = (long long)blockIdx.x * blockDim.x + threadIdx.x; g < ng; g += stride) {
        const long long e = g << 2;
        if (e + 3 < ne) {
            int4 s4 = *(const int4*)(srcp + e);
            int4 d4 = *(const int4*)(dstp + e);
            float4 w4 = *(const float4*)(w + e);
            int s[4] = {s4.x, s4.y, s4.z, s4.w};
            int d[4] = {d4.x, d4.y, d4.z, d4.w};
            float wv[4] = {w4.x, w4.y, w4.z, w4.w};
#pragma unroll
            for (int j = 0; j < 4; ++j) {
                float wn = (s[j] != d[j]) ? -(dinv[s[j]] * wv[j] * dinv[d[j]]) : 0.0f;
                float2 xv = xin[s[j]];
                atomAddF(&acc[2 * d[j] + 0], wn * xv.x);
                atomAddF(&acc[2 * d[j] + 1], wn * xv.y);
            }
        } else {
            for (long long q = e; q < ne; ++q) {
                int ss = srcp[q], dd = dstp[q];
                float wn = (ss != dd) ? -(dinv[ss] * w[q] * dinv[dd]) : 0.0f;
                float2 xv = xin[ss];
                atomAddF(&acc[2 * dd + 0], wn * xv.x);
                atomAddF(&acc[2 * dd + 1], wn * xv.y);
            }
        }
    }
}

__global__ void k_final(const float2* __restrict__ x, const float2* __restrict__ tx1,
                        const float2* __restrict__ tx2a,
                        const float* __restrict__ Wxz, const float* __restrict__ Wxh,
                        const float* __restrict__ bxz, const float* __restrict__ bhz,
                        const float* __restrict__ bxh, const float* __restrict__ bhh,
                        float* __restrict__ out, int n)
{
    int i = blockIdx.x * blockDim.x + threadIdx.x;
    if (i >= n) return;
    float2 t0 = x[i];
    float2 t1 = tx1[i];
    float2 ta = tx2a[i];
    float t2x = 2.0f * ta.x - t0.x;
    float t2y = 2.0f * ta.y - t0.y;
    float z = t0.x * Wxz[0] + t0.y * Wxz[1]
            + t1.x * Wxz[2] + t1.y * Wxz[3]
            + t2x  * Wxz[4] + t2y  * Wxz[5] + bxz[0] + bhz[0];
    float h = t0.x * Wxh[0] + t0.y * Wxh[1]
            + t1.x * Wxh[2] + t1.y * Wxh[3]
            + t2x  * Wxh[4] + t2y  * Wxh[5] + bxh[0] + bhh[0];
    float zs = 1.0f / (1.0f + expf(-z));
    float ht = tanhf(h);
    out[i] = (1.0f - zs) * ht;
}

// ---------------- launch ----------------

struct Lay {
    uint2 *recD, *recS;
    float* dinv;
    float2 *y0, *y1, *tx1;
    float* part;               // split partials (deg: float, prop: float2)
    int *histS, *histD, *baseS, *baseD, *curS, *curD;
    size_t need;
};

static Lay make_layout(char* ws, long long ne, int n, int NBC, bool two_rec, int split)
{
    Lay L{};
    size_t off = 0;
    auto alloc = [&](size_t bytes) -> char* {
        char* p = ws + off;
        off = (off + bytes + 255) & ~(size_t)255;
        return p;
    };
    L.recD = (uint2*)alloc((size_t)ne * sizeof(uint2));
    L.recS = two_rec ? (uint2*)alloc((size_t)ne * sizeof(uint2)) : L.recD;
    L.dinv = (float*)alloc((size_t)n * sizeof(float));
    L.y0   = (float2*)alloc((size_t)n * sizeof(float2));
    L.y1   = (float2*)alloc((size_t)n * sizeof(float2));
    L.tx1  = (float2*)alloc((size_t)n * sizeof(float2));
    L.part = (float*)alloc((size_t)NBC * split * BSIZE * sizeof(float2));
    L.histS = (int*)alloc(NBC_MAX * sizeof(int));
    L.histD = (int*)alloc(NBC_MAX * sizeof(int));
    L.baseS = (int*)alloc(NBC_MAX * sizeof(int));
    L.baseD = (int*)alloc(NBC_MAX * sizeof(int));
    L.curS  = (int*)alloc(NBC_MAX * sizeof(int));
    L.curD  = (int*)alloc(NBC_MAX * sizeof(int));
    L.need = off;
    return L;
}

extern "C" void kernel_launch(void* const* d_in, const int* in_sizes, int n_in,
                              void* d_out, int out_size, void* d_ws, size_t ws_size,
                              hipStream_t stream)
{
    const float* x   = (const float*)d_in[0];
    const int*   ei  = (const int*)d_in[1];
    const float* w   = (const float*)d_in[2];
    const float* Wxz = (const float*)d_in[3];
    const float* Wxh = (const float*)d_in[5];
    const float* bxz = (const float*)d_in[9];
    const float* bhz = (const float*)d_in[10];
    const float* bxh = (const float*)d_in[13];
    const float* bhh = (const float*)d_in[14];

    const int n = in_sizes[0] / 2;
    const long long ne = in_sizes[2];
    const int* srcp = ei;
    const int* dstp = ei + ne;
    const int nblocks = (n + BLK - 1) / BLK;
    const int NBC = (n + BSIZE - 1) >> BSHIFT;
    const int NCH = (int)((ne + SCH - 1) / SCH);
    char* ws = (char*)d_ws;

    const bool nodes_ok = (n <= (1 << 19)) && (NBC <= NBC_MAX);

    // config preference: (two_rec, split8) > (two_rec,4) > (two_rec,1) >
    // (one_rec,4) > atomic fallback
    bool two_rec = true;
    int split = 8;
    Lay L = make_layout(ws, ne, n, NBC, true, 8);
    bool ok = nodes_ok && L.need <= ws_size;
    if (nodes_ok && !ok) {
        L = make_layout(ws, ne, n, NBC, true, 4); split = 4;
        ok = L.need <= ws_size;
    }
    if (nodes_ok && !ok) {
        L = make_layout(ws, ne, n, NBC, true, 1); split = 1;
        ok = L.need <= ws_size;
    }
    if (nodes_ok && !ok) {
        L = make_layout(ws, ne, n, NBC, false, 4); two_rec = false; split = 4;
        ok = L.need <= ws_size;
    }

    if (ok) {
        k_zero_ints<<<(2 * NBC_MAX + BLK - 1) / BLK, BLK, 0, stream>>>(L.histS, 2 * NBC_MAX);
        k_hist<<<2048, BLK, 0, stream>>>(srcp, dstp, L.histS, L.histD, ne, NBC);
        k_scan<<<2, BLK, 0, stream>>>(L.histS, L.baseS, L.curS, L.histD, L.baseD, L.curD, NBC);
        if (two_rec) {
            k_sortscatter<3><<<NCH, BLK, 0, stream>>>(srcp, dstp, w, L.curS, L.curD,
                                                      L.recS, L.recD, ne, NBC, NCH);
            k_degacc<<<NBC * split, BLK_ACC, 0, stream>>>(L.recS, L.baseS, L.histS,
                                                          L.part, split);
            k_degfin<<<nblocks, BLK, 0, stream>>>(L.part, (const float2*)x,
                                                  L.dinv, L.y0, n, split);
        } else {
            k_sortscatter<1><<<NCH, BLK, 0, stream>>>(srcp, dstp, w, L.curS, L.curD,
                                                      L.recS, L.recD, ne, NBC, NCH);
            k_degacc<<<NBC * split, BLK_ACC, 0, stream>>>(L.recS, L.baseS, L.histS,
                                                          L.part, split);
            k_degfin<<<nblocks, BLK, 0, stream>>>(L.part, (const float2*)x,
                                                  L.dinv, L.y0, n, split);
            k_sortscatter<2><<<NCH, BLK, 0, stream>>>(srcp, dstp, w, L.curS, L.curD,
                                                      L.recS, L.recD, ne, NBC, NCH);
        }
        k_propacc<<<NBC * split, BLK_ACC, 0, stream>>>(L.recD, L.baseD, L.histD,
                                                       L.y0, (float2*)L.part, split);
        k_propfin1<<<nblocks, BLK, 0, stream>>>((const float2*)L.part, L.dinv,
                                                L.tx1, L.y1, n, split);
        k_propacc<<<NBC * split, BLK_ACC, 0, stream>>>(L.recD, L.baseD, L.histD,
                                                       L.y1, (float2*)L.part, split);
        k_propfin2<<<nblocks, BLK, 0, stream>>>((const float2*)L.part, L.dinv,
                                                (const float2*)x, L.tx1,
                                                Wxz, Wxh, bxz, bhz, bxh, bhh,
                                                (float*)d_out, n, split);
    } else {
        // last-resort: global-atomic path
        size_t foff = 0;
        auto falloc = [&](size_t bytes) -> char* {
            char* p = ws + foff;
            foff = (foff + bytes + 255) & ~(size_t)255;
            return p;
        };
        float* deg   = (float*)falloc((size_t)n * sizeof(float));
        float* ftx1  = (float*)falloc((size_t)n * 2 * sizeof(float));
        float* ftx2a = (float*)falloc((size_t)n * 2 * sizeof(float));
        const long long n4 = (long long)(foff / 16);
        k_zero_f4<<<1024, BLK, 0, stream>>>((float4*)ws, n4);
        k_deg_atomic<<<4096, BLK, 0, stream>>>(srcp, dstp, w, deg, ne);
        k_dinv_inplace<<<nblocks, BLK, 0, stream>>>(deg, n);
        k_prop_atomic<<<4096, BLK, 0, stream>>>(srcp, dstp, w, deg,
                                                (const float2*)x, ftx1, ne);
        k_prop_atomic<<<4096, BLK, 0, stream>>>(srcp, dstp, w, deg,
                                                (const float2*)ftx1, ftx2a, ne);
        k_final<<<nblocks, BLK, 0, stream>>>((const float2*)x, (const float2*)ftx1,
                                             (const float2*)ftx2a,
                                             Wxz, Wxh, bxz, bhz, bxh, bhh,
                                             (float*)d_out, n);
    }
}

// Round 7
// 685.016 us; speedup vs baseline: 5.7091x; 1.1346x over previous
//
#include <hip/hip_runtime.h>

// GConvGRU (ChebConv K=3, GRU with H=0) on MI355X.
// H=0 => out = (1 - sigmoid(Cz + bhz)) * tanh(Ch + bhh); Cz/Ch share the
// Chebyshev basis Tx0=x, Tx1=P x, Tx2=2 P Tx1 - x, P = -D^{-1/2} A D^{-1/2}.
// Factorization: P v = -dinv .* (A_w^T (dinv .* v)), so records store raw w.
//
// Round-6: sortscatter occupancy-bound (Occ 30%, 12 waves/CU: 48KB LDS with
// 256-thr blocks). This round: 512-thr blocks (same LDS -> 24 waves/CU),
// lrank merged into loff (atomic cursor), and 4-byte src-partition records
// (w truncated to 22 bits | srcLocal 10 bits) halving recS traffic.

static constexpr int BLK = 256;
static constexpr int BLK_SS = 512;      // sortscatter block
static constexpr int BLK_ACC = 512;
static constexpr int NBC_MAX = 512;     // max coarse buckets (n <= 2^19)
static constexpr int BSHIFT = 10;       // 1024 nodes/bucket
static constexpr int BSIZE = 1024;
static constexpr int SCH = 4096;        // edges per sort-scatter chunk

__device__ __forceinline__ void atomAddF(float* p, float v) {
    unsafeAtomicAdd(p, v);
}

// ---------------- utility ----------------

__global__ void k_zero_ints(int* __restrict__ p, int n)
{
    int i = blockIdx.x * blockDim.x + threadIdx.x;
    if (i < n) p[i] = 0;
}

__global__ void k_zero_f4(float4* __restrict__ p, long long n4)
{
    long long i = (long long)blockIdx.x * blockDim.x + threadIdx.x;
    long long stride = (long long)gridDim.x * blockDim.x;
    for (; i < n4; i += stride) p[i] = make_float4(0.f, 0.f, 0.f, 0.f);
}

// ---------------- histogram + scan ----------------

__global__ void k_hist(const int* __restrict__ srcp, const int* __restrict__ dstp,
                       int* __restrict__ histS, int* __restrict__ histD,
                       long long ne, int NB)
{
    __shared__ int lS[NBC_MAX];
    __shared__ int lD[NBC_MAX];
    for (int b = threadIdx.x; b < NB; b += blockDim.x) { lS[b] = 0; lD[b] = 0; }
    __syncthreads();

    const long long ng = (ne + 3) >> 2;
    const long long stride = (long long)gridDim.x * blockDim.x;
    for (long long g = (long long)blockIdx.x * blockDim.x + threadIdx.x; g < ng; g += stride) {
        const long long e = g << 2;
        if (e + 3 < ne) {
            int4 s4 = *(const int4*)(srcp + e);
            int4 d4 = *(const int4*)(dstp + e);
            atomicAdd(&lS[s4.x >> BSHIFT], 1); atomicAdd(&lS[s4.y >> BSHIFT], 1);
            atomicAdd(&lS[s4.z >> BSHIFT], 1); atomicAdd(&lS[s4.w >> BSHIFT], 1);
            atomicAdd(&lD[d4.x >> BSHIFT], 1); atomicAdd(&lD[d4.y >> BSHIFT], 1);
            atomicAdd(&lD[d4.z >> BSHIFT], 1); atomicAdd(&lD[d4.w >> BSHIFT], 1);
        } else {
            for (long long q = e; q < ne; ++q) {
                atomicAdd(&lS[srcp[q] >> BSHIFT], 1);
                atomicAdd(&lD[dstp[q] >> BSHIFT], 1);
            }
        }
    }
    __syncthreads();
    for (int b = threadIdx.x; b < NB; b += blockDim.x) {
        if (lS[b]) atomicAdd(&histS[b], lS[b]);
        if (lD[b]) atomicAdd(&histD[b], lD[b]);
    }
}

// Exclusive scan: block 0 does S, block 1 does D. NB <= 512, BLK=256.
__global__ void k_scan(const int* __restrict__ histS, int* __restrict__ baseS, int* __restrict__ curS,
                       const int* __restrict__ histD, int* __restrict__ baseD, int* __restrict__ curD,
                       int NB)
{
    const int* hist = (blockIdx.x == 0) ? histS : histD;
    int* base = (blockIdx.x == 0) ? baseS : baseD;
    int* cur  = (blockIdx.x == 0) ? curS  : curD;

    __shared__ int part[BLK];
    int t = threadIdx.x;
    int v0 = (2 * t     < NB) ? hist[2 * t]     : 0;
    int v1 = (2 * t + 1 < NB) ? hist[2 * t + 1] : 0;
    part[t] = v0 + v1;
    __syncthreads();
    for (int off = 1; off < BLK; off <<= 1) {
        int val = (t >= off) ? part[t - off] : 0;
        __syncthreads();
        part[t] += val;
        __syncthreads();
    }
    int run = (t == 0) ? 0 : part[t - 1];
    if (2 * t < NB)     { base[2 * t] = run;          cur[2 * t] = run; }
    if (2 * t + 1 < NB) { base[2 * t + 1] = run + v0; cur[2 * t + 1] = run + v0; }
}

// ---------------- LDS-sorted scatter ----------------
// phase 0 (MODE&1): src-partition -> recS (4B): (w & 0xFFFFFC00) | srcLocal
// phase 1 (MODE&2): dst-partition -> recD (8B): { src | dstLocal<<19, w }
// Each block sorts its SCH-edge chunk in LDS, then flushes bucket-contiguous.
// Chunk order is XCD-swizzled (bijective) so adjacent appends share an L2.
template <int MODE>
__global__ __launch_bounds__(BLK_SS)
void k_sortscatter(const int* __restrict__ srcp, const int* __restrict__ dstp,
                   const float* __restrict__ w,
                   int* __restrict__ curS, int* __restrict__ curD,
                   unsigned* __restrict__ recS, uint2* __restrict__ recD,
                   long long ne, int NB, int NCH)
{
    __shared__ uint2 stage[SCH];            // 32 KB (phase1); phase0 aliases 16 KB
    __shared__ unsigned short slotbkt[SCH]; // 8 KB
    __shared__ int loff[NBC_MAX];           // excl offsets -> atomic cursors
    __shared__ int gdelta[NBC_MAX];
    __shared__ int stmp[BLK_SS];
    unsigned* stage0 = (unsigned*)stage;

    const int orig = blockIdx.x;
    const int xcd = orig & 7, idx = orig >> 3;
    const int q8 = NCH >> 3, r8 = NCH & 7;
    const int chunk = (xcd < r8 ? xcd * (q8 + 1) : r8 * (q8 + 1) + (xcd - r8) * q8) + idx;

    const long long cs = (long long)chunk * SCH;
    if (cs >= ne) return;
    const int cnt_chunk = (int)(((cs + SCH) < ne) ? SCH : (ne - cs));
    const int t = threadIdx.x;

    for (int phase = 0; phase < 2; ++phase) {
        if (!(MODE & (1 << phase))) continue;
        const int* keys = phase ? dstp : srcp;
        int* cur = phase ? curD : curS;

        for (int b = t; b < NB; b += BLK_SS) loff[b] = 0;
        __syncthreads();

        // pass 1: count
        for (int i = t * 4; i < cnt_chunk; i += BLK_SS * 4) {
            if (i + 3 < cnt_chunk) {
                int4 k4 = *(const int4*)(keys + cs + i);
                atomicAdd(&loff[k4.x >> BSHIFT], 1); atomicAdd(&loff[k4.y >> BSHIFT], 1);
                atomicAdd(&loff[k4.z >> BSHIFT], 1); atomicAdd(&loff[k4.w >> BSHIFT], 1);
            } else {
                for (int q = i; q < cnt_chunk; ++q)
                    atomicAdd(&loff[keys[cs + q] >> BSHIFT], 1);
            }
        }
        __syncthreads();

        // scan counts (1 bucket/thread) -> excl offsets; reserve global space
        int v = (t < NB) ? loff[t] : 0;
        stmp[t] = v;
        __syncthreads();
        for (int off = 1; off < BLK_SS; off <<= 1) {
            int val = (t >= off) ? stmp[t - off] : 0;
            __syncthreads();
            stmp[t] += val;
            __syncthreads();
        }
        int excl = stmp[t] - v;
        if (t < NB) {
            int g = (v > 0) ? atomicAdd(&cur[t], v) : 0;
            loff[t] = excl;          // becomes the place cursor
            gdelta[t] = g - excl;
        }
        __syncthreads();

        // pass 2: place records bucket-sorted (loff is the cursor)
        for (int i = t * 4; i < cnt_chunk; i += BLK_SS * 4) {
            if (i + 3 < cnt_chunk) {
                int4 s4 = *(const int4*)(srcp + cs + i);
                int4 d4 = *(const int4*)(dstp + cs + i);
                float4 w4 = *(const float4*)(w + cs + i);
                int ss[4] = {s4.x, s4.y, s4.z, s4.w};
                int dd[4] = {d4.x, d4.y, d4.z, d4.w};
                float wv[4] = {w4.x, w4.y, w4.z, w4.w};
#pragma unroll
                for (int j = 0; j < 4; ++j) {
                    float we = (ss[j] == dd[j]) ? 0.0f : wv[j];
                    int key = phase ? dd[j] : ss[j];
                    int b = key >> BSHIFT;
                    int pos = atomicAdd(&loff[b], 1);
                    if (phase) {
                        stage[pos] = make_uint2(
                            (unsigned)ss[j] | ((unsigned)(dd[j] & (BSIZE - 1)) << 19),
                            __float_as_uint(we));
                    } else {
                        stage0[pos] = (__float_as_uint(we) & 0xFFFFFC00u)
                                    | (unsigned)(ss[j] & (BSIZE - 1));
                    }
                    slotbkt[pos] = (unsigned short)b;
                }
            } else {
                for (int q = i; q < cnt_chunk; ++q) {
                    int s = srcp[cs + q], d = dstp[cs + q];
                    float we = (s == d) ? 0.0f : w[cs + q];
                    int key = phase ? d : s;
                    int b = key >> BSHIFT;
                    int pos = atomicAdd(&loff[b], 1);
                    if (phase) {
                        stage[pos] = make_uint2(
                            (unsigned)s | ((unsigned)(d & (BSIZE - 1)) << 19),
                            __float_as_uint(we));
                    } else {
                        stage0[pos] = (__float_as_uint(we) & 0xFFFFFC00u)
                                    | (unsigned)(s & (BSIZE - 1));
                    }
                    slotbkt[pos] = (unsigned short)b;
                }
            }
        }
        __syncthreads();

        // pass 3: flush (runs are time- and address-contiguous)
        for (int i = t; i < cnt_chunk; i += BLK_SS) {
            int b = slotbkt[i];
            if (phase) recD[(long long)(i + gdelta[b])] = stage[i];
            else       recS[(long long)(i + gdelta[b])] = stage0[i];
        }
        __syncthreads();
    }
}

// ---------------- split accumulate + combine ----------------

// deg partial from 4B records.
__global__ __launch_bounds__(BLK_ACC)
void k_degacc(const unsigned* __restrict__ recs, const int* __restrict__ base,
              const int* __restrict__ hist, float* __restrict__ part, int split)
{
    __shared__ float lacc[BSIZE];
    const int b = blockIdx.x / split, sp = blockIdx.x % split;
    for (int i = threadIdx.x; i < BSIZE; i += blockDim.x) lacc[i] = 0.0f;
    __syncthreads();
    const int st = base[b], cnt = hist[b];
    const int i0 = (int)((long long)cnt * sp / split);
    const int i1 = (int)((long long)cnt * (sp + 1) / split);
    for (int r = i0 + threadIdx.x; r < i1; r += blockDim.x) {
        unsigned rec = recs[(long long)st + r];
        atomicAdd(&lacc[rec & (BSIZE - 1u)], __uint_as_float(rec & 0xFFFFFC00u));
    }
    __syncthreads();
    float* dst = part + (size_t)(b * split + sp) * BSIZE;
    for (int i = threadIdx.x; i < BSIZE; i += blockDim.x) dst[i] = lacc[i];
}

// combine deg partials -> dinv, y0 = dinv*x
__global__ void k_degfin(const float* __restrict__ part, const float2* __restrict__ x,
                         float* __restrict__ dinv, float2* __restrict__ y0,
                         int n, int split)
{
    int node = blockIdx.x * blockDim.x + threadIdx.x;
    if (node >= n) return;
    int b = node >> BSHIFT, loc = node & (BSIZE - 1);
    float dg = 0.0f;
    for (int sp = 0; sp < split; ++sp)
        dg += part[(size_t)(b * split + sp) * BSIZE + loc];
    float di = (dg > 0.0f) ? rsqrtf(dg) : 0.0f;
    dinv[node] = di;
    float2 xv = x[node];
    y0[node] = make_float2(di * xv.x, di * xv.y);
}

// prop partial: part[(b*split+sp)*BSIZE + loc] = sum of w * yin[src]
__global__ __launch_bounds__(BLK_ACC)
void k_propacc(const uint2* __restrict__ recs, const int* __restrict__ base,
               const int* __restrict__ hist, const float2* __restrict__ yin,
               float2* __restrict__ part, int split)
{
    __shared__ float lax[BSIZE];
    __shared__ float lay[BSIZE];
    const int b = blockIdx.x / split, sp = blockIdx.x % split;
    for (int i = threadIdx.x; i < BSIZE; i += blockDim.x) { lax[i] = 0.0f; lay[i] = 0.0f; }
    __syncthreads();
    const int st = base[b], cnt = hist[b];
    const int i0 = (int)((long long)cnt * sp / split);
    const int i1 = (int)((long long)cnt * (sp + 1) / split);
    for (int r = i0 + threadIdx.x; r < i1; r += blockDim.x) {
        uint2 rec = recs[(long long)st + r];
        int s  = (int)(rec.x & 0x7FFFFu);
        int dl = (int)(rec.x >> 19);
        float wv = __uint_as_float(rec.y);
        float2 yv = yin[s];
        atomicAdd(&lax[dl], wv * yv.x);
        atomicAdd(&lay[dl], wv * yv.y);
    }
    __syncthreads();
    float2* dst = part + (size_t)(b * split + sp) * BSIZE;
    for (int i = threadIdx.x; i < BSIZE; i += blockDim.x)
        dst[i] = make_float2(lax[i], lay[i]);
}

// combine prop1 partials -> tx1 = -dinv*sum, y1 = dinv*tx1
__global__ void k_propfin1(const float2* __restrict__ part, const float* __restrict__ dinv,
                           float2* __restrict__ tx1, float2* __restrict__ y1,
                           int n, int split)
{
    int node = blockIdx.x * blockDim.x + threadIdx.x;
    if (node >= n) return;
    int b = node >> BSHIFT, loc = node & (BSIZE - 1);
    float sx = 0.0f, sy = 0.0f;
    for (int sp = 0; sp < split; ++sp) {
        float2 v = part[(size_t)(b * split + sp) * BSIZE + loc];
        sx += v.x; sy += v.y;
    }
    float di = dinv[node];
    float ox = -di * sx, oy = -di * sy;
    tx1[node] = make_float2(ox, oy);
    y1[node] = make_float2(di * ox, di * oy);
}

// combine prop2 partials + fused gates -> out
__global__ void k_propfin2(const float2* __restrict__ part, const float* __restrict__ dinv,
                           const float2* __restrict__ x, const float2* __restrict__ tx1,
                           const float* __restrict__ Wxz, const float* __restrict__ Wxh,
                           const float* __restrict__ bxz, const float* __restrict__ bhz,
                           const float* __restrict__ bxh, const float* __restrict__ bhh,
                           float* __restrict__ out, int n, int split)
{
    int node = blockIdx.x * blockDim.x + threadIdx.x;
    if (node >= n) return;
    int b = node >> BSHIFT, loc = node & (BSIZE - 1);
    float sx = 0.0f, sy = 0.0f;
    for (int sp = 0; sp < split; ++sp) {
        float2 v = part[(size_t)(b * split + sp) * BSIZE + loc];
        sx += v.x; sy += v.y;
    }
    float di = dinv[node];
    float2 t0 = x[node];
    float2 t1 = tx1[node];
    float t2x = 2.0f * (-di * sx) - t0.x;
    float t2y = 2.0f * (-di * sy) - t0.y;
    float z = t0.x * Wxz[0] + t0.y * Wxz[1]
            + t1.x * Wxz[2] + t1.y * Wxz[3]
            + t2x  * Wxz[4] + t2y  * Wxz[5] + bxz[0] + bhz[0];
    float h = t0.x * Wxh[0] + t0.y * Wxh[1]
            + t1.x * Wxh[2] + t1.y * Wxh[3]
            + t2x  * Wxh[4] + t2y  * Wxh[5] + bxh[0] + bhh[0];
    float zs = 1.0f / (1.0f + expf(-z));
    float ht = tanhf(h);
    out[node] = (1.0f - zs) * ht;
}

// ---------------- atomic fallback ----------------

__global__ void k_deg_atomic(const int* __restrict__ srcp, const int* __restrict__ dstp,
                             const float* __restrict__ w, float* __restrict__ deg,
                             long long ne)
{
    const long long ng = (ne + 3) >> 2;
    const long long stride = (long long)gridDim.x * blockDim.x;
    for (long long g = (long long)blockIdx.x * blockDim.x + threadIdx.x; g < ng; g += stride) {
        const long long e = g << 2;
        if (e + 3 < ne) {
            int4 s4 = *(const int4*)(srcp + e);
            int4 d4 = *(const int4*)(dstp + e);
            float4 w4 = *(const float4*)(w + e);
            if (s4.x != d4.x) atomAddF(&deg[s4.x], w4.x);
            if (s4.y != d4.y) atomAddF(&deg[s4.y], w4.y);
            if (s4.z != d4.z) atomAddF(&deg[s4.z], w4.z);
            if (s4.w != d4.w) atomAddF(&deg[s4.w], w4.w);
        } else {
            for (long long q = e; q < ne; ++q) {
                int s = srcp[q], d = dstp[q];
                if (s != d) atomAddF(&deg[s], w[q]);
            }
        }
    }
}

__global__ void k_dinv_inplace(float* __restrict__ deg, int n)
{
    int i = blockIdx.x * blockDim.x + threadIdx.x;
    if (i < n) {
        float d = deg[i];
        deg[i] = (d > 0.0f) ? rsqrtf(d) : 0.0f;
    }
}

__global__ void k_prop_atomic(const int* __restrict__ srcp, const int* __restrict__ dstp,
                              const float* __restrict__ w, const float* __restrict__ dinv,
                              const float2* __restrict__ xin, float* __restrict__ acc,
                              long long ne)
{
    const long long ng = (ne + 3) >> 2;
    const long long stride = (long long)gridDim.x * blockDim.x;
    for (long long g = (long long)blockIdx.x * blockDim.x + threadIdx.x; g < ng; g += stride) {
        const long long e = g << 2;
        if (e + 3 < ne) {
            int4 s4 = *(const int4*)(srcp + e);
            int4 d4 = *(const int4*)(dstp + e);
            float4 w4 = *(const float4*)(w + e);
            int s[4] = {s4.x, s4.y, s4.z, s4.w};
            int d[4] = {d4.x, d4.y, d4.z, d4.w};
            float wv[4] = {w4.x, w4.y, w4.z, w4.w};
#pragma unroll
            for (int j = 0; j < 4; ++j) {
                float wn = (s[j] != d[j]) ? -(dinv[s[j]] * wv[j] * dinv[d[j]]) : 0.0f;
                float2 xv = xin[s[j]];
                atomAddF(&acc[2 * d[j] + 0], wn * xv.x);
                atomAddF(&acc[2 * d[j] + 1], wn * xv.y);
            }
        } else {
            for (long long q = e; q < ne; ++q) {
                int ss = srcp[q], dd = dstp[q];
                float wn = (ss != dd) ? -(dinv[ss] * w[q] * dinv[dd]) : 0.0f;
                float2 xv = xin[ss];
                atomAddF(&acc[2 * dd + 0], wn * xv.x);
                atomAddF(&acc[2 * dd + 1], wn * xv.y);
            }
        }
    }
}

__global__ void k_final(const float2* __restrict__ x, const float2* __restrict__ tx1,
                        const float2* __restrict__ tx2a,
                        const float* __restrict__ Wxz, const float* __restrict__ Wxh,
                        const float* __restrict__ bxz, const float* __restrict__ bhz,
                        const float* __restrict__ bxh, const float* __restrict__ bhh,
                        float* __restrict__ out, int n)
{
    int i = blockIdx.x * blockDim.x + threadIdx.x;
    if (i >= n) return;
    float2 t0 = x[i];
    float2 t1 = tx1[i];
    float2 ta = tx2a[i];
    float t2x = 2.0f * ta.x - t0.x;
    float t2y = 2.0f * ta.y - t0.y;
    float z = t0.x * Wxz[0] + t0.y * Wxz[1]
            + t1.x * Wxz[2] + t1.y * Wxz[3]
            + t2x  * Wxz[4] + t2y  * Wxz[5] + bxz[0] + bhz[0];
    float h = t0.x * Wxh[0] + t0.y * Wxh[1]
            + t1.x * Wxh[2] + t1.y * Wxh[3]
            + t2x  * Wxh[4] + t2y  * Wxh[5] + bxh[0] + bhh[0];
    float zs = 1.0f / (1.0f + expf(-z));
    float ht = tanhf(h);
    out[i] = (1.0f - zs) * ht;
}

// ---------------- launch ----------------

struct Lay {
    uint2* recD;
    unsigned* recS;
    float* dinv;
    float2 *y0, *y1, *tx1;
    float* part;               // split partials (deg: float, prop: float2)
    int *histS, *histD, *baseS, *baseD, *curS, *curD;
    size_t need;
};

static Lay make_layout(char* ws, long long ne, int n, int NBC, bool two_rec, int split)
{
    Lay L{};
    size_t off = 0;
    auto alloc = [&](size_t bytes) -> char* {
        char* p = ws + off;
        off = (off + bytes + 255) & ~(size_t)255;
        return p;
    };
    L.recD = (uint2*)alloc((size_t)ne * sizeof(uint2));
    L.recS = two_rec ? (unsigned*)alloc((size_t)ne * sizeof(unsigned))
                     : (unsigned*)L.recD;     // one_rec: recS lives in recD space
    L.dinv = (float*)alloc((size_t)n * sizeof(float));
    L.y0   = (float2*)alloc((size_t)n * sizeof(float2));
    L.y1   = (float2*)alloc((size_t)n * sizeof(float2));
    L.tx1  = (float2*)alloc((size_t)n * sizeof(float2));
    L.part = (float*)alloc((size_t)NBC * split * BSIZE * sizeof(float2));
    L.histS = (int*)alloc(NBC_MAX * sizeof(int));
    L.histD = (int*)alloc(NBC_MAX * sizeof(int));
    L.baseS = (int*)alloc(NBC_MAX * sizeof(int));
    L.baseD = (int*)alloc(NBC_MAX * sizeof(int));
    L.curS  = (int*)alloc(NBC_MAX * sizeof(int));
    L.curD  = (int*)alloc(NBC_MAX * sizeof(int));
    L.need = off;
    return L;
}

extern "C" void kernel_launch(void* const* d_in, const int* in_sizes, int n_in,
                              void* d_out, int out_size, void* d_ws, size_t ws_size,
                              hipStream_t stream)
{
    const float* x   = (const float*)d_in[0];
    const int*   ei  = (const int*)d_in[1];
    const float* w   = (const float*)d_in[2];
    const float* Wxz = (const float*)d_in[3];
    const float* Wxh = (const float*)d_in[5];
    const float* bxz = (const float*)d_in[9];
    const float* bhz = (const float*)d_in[10];
    const float* bxh = (const float*)d_in[13];
    const float* bhh = (const float*)d_in[14];

    const int n = in_sizes[0] / 2;
    const long long ne = in_sizes[2];
    const int* srcp = ei;
    const int* dstp = ei + ne;
    const int nblocks = (n + BLK - 1) / BLK;
    const int NBC = (n + BSIZE - 1) >> BSHIFT;
    const int NCH = (int)((ne + SCH - 1) / SCH);
    char* ws = (char*)d_ws;

    const bool nodes_ok = (n <= (1 << 19)) && (NBC <= NBC_MAX);

    // config preference: (two_rec, split8) > (two_rec,4) > (two_rec,1) >
    // (one_rec,4) > atomic fallback
    bool two_rec = true;
    int split = 8;
    Lay L = make_layout(ws, ne, n, NBC, true, 8);
    bool ok = nodes_ok && L.need <= ws_size;
    if (nodes_ok && !ok) {
        L = make_layout(ws, ne, n, NBC, true, 4); split = 4;
        ok = L.need <= ws_size;
    }
    if (nodes_ok && !ok) {
        L = make_layout(ws, ne, n, NBC, true, 1); split = 1;
        ok = L.need <= ws_size;
    }
    if (nodes_ok && !ok) {
        L = make_layout(ws, ne, n, NBC, false, 4); two_rec = false; split = 4;
        ok = L.need <= ws_size;
    }

    if (ok) {
        k_zero_ints<<<(2 * NBC_MAX + BLK - 1) / BLK, BLK, 0, stream>>>(L.histS, 2 * NBC_MAX);
        k_hist<<<2048, BLK, 0, stream>>>(srcp, dstp, L.histS, L.histD, ne, NBC);
        k_scan<<<2, BLK, 0, stream>>>(L.histS, L.baseS, L.curS, L.histD, L.baseD, L.curD, NBC);
        if (two_rec) {
            k_sortscatter<3><<<NCH, BLK_SS, 0, stream>>>(srcp, dstp, w, L.curS, L.curD,
                                                         L.recS, L.recD, ne, NBC, NCH);
            k_degacc<<<NBC * split, BLK_ACC, 0, stream>>>(L.recS, L.baseS, L.histS,
                                                          L.part, split);
            k_degfin<<<nblocks, BLK, 0, stream>>>(L.part, (const float2*)x,
                                                  L.dinv, L.y0, n, split);
        } else {
            // one_rec: 4B src records in recD's space, consumed before recD write
            k_sortscatter<1><<<NCH, BLK_SS, 0, stream>>>(srcp, dstp, w, L.curS, L.curD,
                                                         L.recS, L.recD, ne, NBC, NCH);
            k_degacc<<<NBC * split, BLK_ACC, 0, stream>>>(L.recS, L.baseS, L.histS,
                                                          L.part, split);
            k_degfin<<<nblocks, BLK, 0, stream>>>(L.part, (const float2*)x,
                                                  L.dinv, L.y0, n, split);
            k_sortscatter<2><<<NCH, BLK_SS, 0, stream>>>(srcp, dstp, w, L.curS, L.curD,
                                                         L.recS, L.recD, ne, NBC, NCH);
        }
        k_propacc<<<NBC * split, BLK_ACC, 0, stream>>>(L.recD, L.baseD, L.histD,
                                                       L.y0, (float2*)L.part, split);
        k_propfin1<<<nblocks, BLK, 0, stream>>>((const float2*)L.part, L.dinv,
                                                L.tx1, L.y1, n, split);
        k_propacc<<<NBC * split, BLK_ACC, 0, stream>>>(L.recD, L.baseD, L.histD,
                                                       L.y1, (float2*)L.part, split);
        k_propfin2<<<nblocks, BLK, 0, stream>>>((const float2*)L.part, L.dinv,
                                                (const float2*)x, L.tx1,
                                                Wxz, Wxh, bxz, bhz, bxh, bhh,
                                                (float*)d_out, n, split);
    } else {
        // last-resort: global-atomic path
        size_t foff = 0;
        auto falloc = [&](size_t bytes) -> char* {
            char* p = ws + foff;
            foff = (foff + bytes + 255) & ~(size_t)255;
            return p;
        };
        float* deg   = (float*)falloc((size_t)n * sizeof(float));
        float* ftx1  = (float*)falloc((size_t)n * 2 * sizeof(float));
        float* ftx2a = (float*)falloc((size_t)n * 2 * sizeof(float));
        const long long n4 = (long long)(foff / 16);
        k_zero_f4<<<1024, BLK, 0, stream>>>((float4*)ws, n4);
        k_deg_atomic<<<4096, BLK, 0, stream>>>(srcp, dstp, w, deg, ne);
        k_dinv_inplace<<<nblocks, BLK, 0, stream>>>(deg, n);
        k_prop_atomic<<<4096, BLK, 0, stream>>>(srcp, dstp, w, deg,
                                                (const float2*)x, ftx1, ne);
        k_prop_atomic<<<4096, BLK, 0, stream>>>(srcp, dstp, w, deg,
                                                (const float2*)ftx1, ftx2a, ne);
        k_final<<<nblocks, BLK, 0, stream>>>((const float2*)x, (const float2*)ftx1,
                                             (const float2*)ftx2a,
                                             Wxz, Wxh, bxz, bhz, bxh, bhh,
                                             (float*)d_out, n);
    }
}